// Round 1
// 250.275 us; speedup vs baseline: 1.0417x; 1.0417x over previous
//
#include <hip/hip_runtime.h>

// GCN 2-layer: x[N,128] -> GCNConv(W1[128,64], b1) -> ReLU -> GCNConv(W2[64,32], b2)
// norm = dinv[src]*dinv[dst] factorized. Bucketed multisplit build (R4), bf16
// intermediates (R5), MFMA gemms (R8), pk-math aggs (R9), dense per-bucket
// edge segments (R10).
// R11: aggs were latency-chain bound (tail loop csr->dinv->H serial, ~2.2
// rounds/wave; VALUBusy 50%, HBM 25%). (a) hs1 pre-scaled by dinv[row] in
// k_gemm1 epilogue (same pattern as gemm2) -> agg1 drops the dinv[src] gather
// and uses pkadd. (b) both aggs preload <=64 csr entries with ONE coalesced
// load, broadcast src ids via __shfl, and issue paired gathers back-to-back:
// per-wave chain csr+shfl+1 gather instead of ~2x(csr+gather).

#define BLK 256
#define BLKC 1024        // k_csr block size
#define EPT 8            // edges/thread in k_part
#define BSHIFT 10        // nodes per bucket
#define NPB 1024         // 1 << BSHIFT
#define SLOTB 18432      // edge slots per bucket; lambda~16.3K, 16 sigma
#define NBMAX 128        // >= nbuck = ceil(N/NPB) = 98

typedef unsigned int uint_t;
typedef unsigned short ushort_t;
typedef __attribute__((ext_vector_type(2))) float v2f;      // v_pk_* pair
typedef __attribute__((ext_vector_type(8))) short bf16x8;   // MFMA A/B frag
typedef __attribute__((ext_vector_type(4))) float f32x4;    // MFMA C/D frag

__device__ __forceinline__ uint_t f2bf(float x) {   // RNE float->bf16 (low 16)
    union { float f; uint_t u; } un; un.f = x;
    uint_t u = un.u;
    return (u + 0x7fffu + ((u >> 16) & 1u)) >> 16;
}

// 8 bf16 (uint4) += into 4 float2 accumulators (v_pk_add_f32 path)
__device__ __forceinline__ void pkadd(v2f& a0, v2f& a1, v2f& a2, v2f& a3, uint4 v) {
    v2f p;
    p.x = __uint_as_float(v.x << 16); p.y = __uint_as_float(v.x & 0xffff0000u); a0 += p;
    p.x = __uint_as_float(v.y << 16); p.y = __uint_as_float(v.y & 0xffff0000u); a1 += p;
    p.x = __uint_as_float(v.z << 16); p.y = __uint_as_float(v.z & 0xffff0000u); a2 += p;
    p.x = __uint_as_float(v.w << 16); p.y = __uint_as_float(v.w & 0xffff0000u); a3 += p;
}

// int64-layout detection (wave-uniform, L2-hot)
__device__ __forceinline__ bool detect64(const int* __restrict__ idx) {
    int z = 0;
#pragma unroll
    for (int i = 1; i < 32; i += 2) z |= idx[i];
    return z == 0;
}

// ---- build pass 1: partition edges into DENSE per-bucket segments.
// LDS histogram -> one global cursor atomicAdd per (block,bucket) to reserve a
// contiguous run at fixed base b*SLOTB -> grouped stores (L2 write-combining).
__global__ void k_part(const int* __restrict__ idx, int* __restrict__ bcursor,
                       int* __restrict__ edge_part, int E, int nbuck) {
    __shared__ int h[NBMAX];
    __shared__ int rb[NBMAX];
    bool is64 = detect64(idx);
    int t = threadIdx.x, blk = blockIdx.x;
    for (int i = t; i < nbuck; i += BLK) h[i] = 0;
    __syncthreads();
    int base = blk * (BLK * EPT) + t;
    int dst[EPT], src[EPT];
#pragma unroll
    for (int k = 0; k < EPT; ++k) {
        int e = base + k * BLK;
        if (e < E) {
            dst[k] = is64 ? idx[2 * (E + e)] : idx[E + e];
            src[k] = is64 ? idx[2 * e] : idx[e];
            atomicAdd(&h[dst[k] >> BSHIFT], 1);
        } else {
            dst[k] = -1;
        }
    }
    __syncthreads();
    for (int i = t; i < nbuck; i += BLK) {
        int c = h[i];
        rb[i] = c ? atomicAdd(&bcursor[i], c) : 0;
        h[i] = 0;
    }
    __syncthreads();
#pragma unroll
    for (int k = 0; k < EPT; ++k) {
        if (dst[k] >= 0) {
            int b = dst[k] >> BSHIFT;
            int r = atomicAdd(&h[b], 1);
            edge_part[(size_t)b * SLOTB + rb[b] + r] =
                src[k] | ((dst[k] & (NPB - 1)) << 17);
        }
    }
}

// ---- build pass 2: one 1024-thread block per bucket; dense coalesced edge
// reads, 16 indep loads/thread/pass; count/scan/fill in LDS; emits row_ptr,
// deg, dinv, csr_src.
__global__ __launch_bounds__(BLKC) void k_csr(
        const int* __restrict__ edge_part, const int* __restrict__ bcursor,
        int* __restrict__ row_ptr, int* __restrict__ deg, float* __restrict__ dinv,
        int* __restrict__ csr_src, int N, int nbuck) {
    __shared__ int cnt[NPB];
    __shared__ int off[NPB];
    int b = blockIdx.x, t = threadIdx.x;
    int node0 = b << BSHIFT;
    int nn = min(NPB, N - node0);
    int m = bcursor[b];                   // total edges in this bucket
    size_t ebase = (size_t)b * SLOTB;
    cnt[t] = 0;
    __syncthreads();
    for (int e = t; e < m; e += BLKC)
        atomicAdd(&cnt[((unsigned)edge_part[ebase + e]) >> 17], 1);
    __syncthreads();
    // inclusive scan of cnt[1024] (1 entry/thread) -> exclusive offsets
    off[t] = cnt[t];
    __syncthreads();
    for (int st = 1; st < BLKC; st <<= 1) {
        int v = (t >= st) ? off[t - st] : 0;
        __syncthreads();
        off[t] += v;
        __syncthreads();
    }
    int excl = off[t] - cnt[t];
    off[t] = excl;                        // own-entry overwrite, no cross-read
    if (t < nn) {
        row_ptr[node0 + t] = (int)(ebase + excl);
        deg[node0 + t] = cnt[t];
        dinv[node0 + t] = rsqrtf((float)(cnt[t] + 1));  // +1 self-loop
    }
    __syncthreads();
    for (int e = t; e < m; e += BLKC) {
        int p = edge_part[ebase + e];
        int dlo = ((unsigned)p) >> 17;
        int r = atomicAdd(&off[dlo], 1);
        csr_src[ebase + r] = p & 0x1FFFF;
    }
}

// ---- layer 1 GEMM (MFMA bf16): 64 rows x 64 cols per block, 4 waves.
// hs1[i,f] = bf16((x @ W1)[i,f] * dinv[i])  -- PRE-SCALED (agg1 adds directly).
__global__ __launch_bounds__(256) void k_gemm1(
        const float* __restrict__ x, const float* __restrict__ W1,
        const float* __restrict__ dinv, ushort_t* __restrict__ hs1, int N) {
    __shared__ ushort_t xb[64][136];   // x tile, bf16 (+pad -> frag reads <=2-way)
    __shared__ ushort_t wb[64][136];   // W1 transposed (wb[n][k]), bf16
    int t = threadIdx.x;
    int rbase = blockIdx.x * 64;
    for (int i = t; i < 2048; i += BLK) {
        int k = i >> 4, n4 = i & 15;
        float4 w = ((const float4*)W1)[i];
        wb[4 * n4 + 0][k] = (ushort_t)f2bf(w.x);
        wb[4 * n4 + 1][k] = (ushort_t)f2bf(w.y);
        wb[4 * n4 + 2][k] = (ushort_t)f2bf(w.z);
        wb[4 * n4 + 3][k] = (ushort_t)f2bf(w.w);
    }
    for (int i = t; i < 2048; i += BLK) {
        int r = i >> 5, c4 = i & 31;
        int rr = rbase + r; if (rr >= N) rr = N - 1;
        float4 v = ((const float4*)x)[(size_t)rr * 32 + c4];
        uint2 p;
        p.x = f2bf(v.x) | (f2bf(v.y) << 16);
        p.y = f2bf(v.z) | (f2bf(v.w) << 16);
        *(uint2*)&xb[r][4 * c4] = p;
    }
    __syncthreads();
    int w = t >> 6, l = t & 63;
    int lane16 = l & 15, quad = l >> 4;
    int mrow = 16 * w + lane16;
    f32x4 acc0 = {0.f, 0.f, 0.f, 0.f}, acc1 = {0.f, 0.f, 0.f, 0.f};
    f32x4 acc2 = {0.f, 0.f, 0.f, 0.f}, acc3 = {0.f, 0.f, 0.f, 0.f};
#pragma unroll
    for (int kk = 0; kk < 4; ++kk) {
        int k0 = kk * 32 + quad * 8;
        bf16x8 a  = *(const bf16x8*)&xb[mrow][k0];
        bf16x8 b0 = *(const bf16x8*)&wb[lane16][k0];
        bf16x8 b1 = *(const bf16x8*)&wb[lane16 + 16][k0];
        bf16x8 b2 = *(const bf16x8*)&wb[lane16 + 32][k0];
        bf16x8 b3 = *(const bf16x8*)&wb[lane16 + 48][k0];
        acc0 = __builtin_amdgcn_mfma_f32_16x16x32_bf16(a, b0, acc0, 0, 0, 0);
        acc1 = __builtin_amdgcn_mfma_f32_16x16x32_bf16(a, b1, acc1, 0, 0, 0);
        acc2 = __builtin_amdgcn_mfma_f32_16x16x32_bf16(a, b2, acc2, 0, 0, 0);
        acc3 = __builtin_amdgcn_mfma_f32_16x16x32_bf16(a, b3, acc3, 0, 0, 0);
    }
    __syncthreads();
    int orow = 16 * w + quad * 4;   // D: row = quad*4+reg, col = lane16 (+16c)
    float d0 = dinv[min(rbase + orow + 0, N - 1)];
    float d1 = dinv[min(rbase + orow + 1, N - 1)];
    float d2 = dinv[min(rbase + orow + 2, N - 1)];
    float d3 = dinv[min(rbase + orow + 3, N - 1)];
    xb[orow + 0][lane16]      = (ushort_t)f2bf(acc0.x * d0);
    xb[orow + 1][lane16]      = (ushort_t)f2bf(acc0.y * d1);
    xb[orow + 2][lane16]      = (ushort_t)f2bf(acc0.z * d2);
    xb[orow + 3][lane16]      = (ushort_t)f2bf(acc0.w * d3);
    xb[orow + 0][lane16 + 16] = (ushort_t)f2bf(acc1.x * d0);
    xb[orow + 1][lane16 + 16] = (ushort_t)f2bf(acc1.y * d1);
    xb[orow + 2][lane16 + 16] = (ushort_t)f2bf(acc1.z * d2);
    xb[orow + 3][lane16 + 16] = (ushort_t)f2bf(acc1.w * d3);
    xb[orow + 0][lane16 + 32] = (ushort_t)f2bf(acc2.x * d0);
    xb[orow + 1][lane16 + 32] = (ushort_t)f2bf(acc2.y * d1);
    xb[orow + 2][lane16 + 32] = (ushort_t)f2bf(acc2.z * d2);
    xb[orow + 3][lane16 + 32] = (ushort_t)f2bf(acc2.w * d3);
    xb[orow + 0][lane16 + 48] = (ushort_t)f2bf(acc3.x * d0);
    xb[orow + 1][lane16 + 48] = (ushort_t)f2bf(acc3.y * d1);
    xb[orow + 2][lane16 + 48] = (ushort_t)f2bf(acc3.z * d2);
    xb[orow + 3][lane16 + 48] = (ushort_t)f2bf(acc3.w * d3);
    __syncthreads();
    for (int i = t; i < 512; i += BLK) {
        int r = i >> 3, c8 = i & 7;
        int rr = rbase + r;
        if (rr < N) {
            uint4 v = *(const uint4*)&xb[r][8 * c8];
            *(uint4*)&hs1[(size_t)rr * 64 + 8 * c8] = v;
        }
    }
}

// ---- layer 1 aggregation: wave/node; 8 groups x 8 lanes. hs1 pre-scaled by
// dinv[src] -> pure pkadd. One coalesced csr preload into lanes, __shfl
// broadcast of src ids, paired gather issue (chain = csr + shfl + 1 gather).
__global__ void k_agg1(const uint_t* __restrict__ hs1, const int* __restrict__ row_ptr,
                       const int* __restrict__ deg, const int* __restrict__ csr_src,
                       const float* __restrict__ dinv, const float* __restrict__ b1,
                       ushort_t* __restrict__ a1b, int N) {
    int node = (blockIdx.x * blockDim.x + threadIdx.x) >> 6;
    if (node >= N) return;
    int lane = threadIdx.x & 63;
    int g = lane >> 3;   // edge slot 0..7
    int c = lane & 7;    // uint4 column: features [8c, 8c+8)
    const uint4* H = (const uint4*)hs1;
    v2f a0 = {0.f, 0.f}, a1_ = {0.f, 0.f}, a2 = {0.f, 0.f}, a3 = {0.f, 0.f};
    float dn = dinv[node];
    int beg = row_ptr[node], tot = deg[node];
    int jal = (lane < tot) ? csr_src[beg + lane] : 0;   // one coalesced load
    if (g == 0) pkadd(a0, a1_, a2, a3, H[(size_t)node * 8 + c]);  // self-loop
    int nt = (tot + 7) >> 3;   // wave-uniform slot-trip bound
    int t = 0;
    for (; t + 1 < nt; t += 2) {
        int s0 = g + 8 * t, s1 = s0 + 8;      // s0 < tot guaranteed here
        int j0 = __shfl(jal, s0 & 63, 64);
        int j1 = __shfl(jal, s1 & 63, 64);
        if (s0 >= 64) j0 = csr_src[beg + s0];
        bool p1 = s1 < tot;
        if (s1 >= 64 && p1) j1 = csr_src[beg + s1];
        uint4 v0 = H[(size_t)j0 * 8 + c];
        uint4 v1;
        if (p1) v1 = H[(size_t)j1 * 8 + c];
        pkadd(a0, a1_, a2, a3, v0);
        if (p1) pkadd(a0, a1_, a2, a3, v1);
    }
    for (; t < nt; ++t) {
        int s = g + 8 * t;
        int j = __shfl(jal, s & 63, 64);
        bool p = s < tot;
        if (s >= 64 && p) j = csr_src[beg + s];
        if (p) pkadd(a0, a1_, a2, a3, H[(size_t)j * 8 + c]);
    }
#pragma unroll
    for (int m = 8; m <= 32; m <<= 1) {
        a0.x += __shfl_xor(a0.x, m, 64); a0.y += __shfl_xor(a0.y, m, 64);
        a1_.x += __shfl_xor(a1_.x, m, 64); a1_.y += __shfl_xor(a1_.y, m, 64);
        a2.x += __shfl_xor(a2.x, m, 64); a2.y += __shfl_xor(a2.y, m, 64);
        a3.x += __shfl_xor(a3.x, m, 64); a3.y += __shfl_xor(a3.y, m, 64);
    }
    if (g == 0) {
        const float4* B = (const float4*)b1;
        float4 bv0 = B[2 * c], bv1 = B[2 * c + 1];
        float o0 = fmaxf(fmaf(a0.x, dn, bv0.x), 0.f);
        float o1 = fmaxf(fmaf(a0.y, dn, bv0.y), 0.f);
        float o2 = fmaxf(fmaf(a1_.x, dn, bv0.z), 0.f);
        float o3 = fmaxf(fmaf(a1_.y, dn, bv0.w), 0.f);
        float o4 = fmaxf(fmaf(a2.x, dn, bv1.x), 0.f);
        float o5 = fmaxf(fmaf(a2.y, dn, bv1.y), 0.f);
        float o6 = fmaxf(fmaf(a3.x, dn, bv1.z), 0.f);
        float o7 = fmaxf(fmaf(a3.y, dn, bv1.w), 0.f);
        uint4 o;
        o.x = f2bf(o0) | (f2bf(o1) << 16);
        o.y = f2bf(o2) | (f2bf(o3) << 16);
        o.z = f2bf(o4) | (f2bf(o5) << 16);
        o.w = f2bf(o6) | (f2bf(o7) << 16);
        ((uint4*)a1b)[(size_t)node * 8 + c] = o;
    }
}

// ---- layer 2 GEMM (MFMA bf16): 64 rows x 32 cols per block, 4 waves.
// hs2[i,f] = bf16((a1 @ W2)[i,f] * dinv[i])  -- pre-scaled (agg2 adds directly).
__global__ __launch_bounds__(256) void k_gemm2(
        const ushort_t* __restrict__ a1b, const float* __restrict__ W2,
        const float* __restrict__ dinv, ushort_t* __restrict__ hs2, int N) {
    __shared__ ushort_t ab[64][72];
    __shared__ ushort_t wb[32][72];
    int t = threadIdx.x;
    int rbase = blockIdx.x * 64;
    for (int i = t; i < 512; i += BLK) {
        int k = i >> 3, n4 = i & 7;
        float4 w = ((const float4*)W2)[i];
        wb[4 * n4 + 0][k] = (ushort_t)f2bf(w.x);
        wb[4 * n4 + 1][k] = (ushort_t)f2bf(w.y);
        wb[4 * n4 + 2][k] = (ushort_t)f2bf(w.z);
        wb[4 * n4 + 3][k] = (ushort_t)f2bf(w.w);
    }
    for (int i = t; i < 512; i += BLK) {
        int r = i >> 3, c8 = i & 7;
        int rr = rbase + r; if (rr >= N) rr = N - 1;
        uint4 v = ((const uint4*)a1b)[(size_t)rr * 8 + c8];
        *(uint4*)&ab[r][8 * c8] = v;
    }
    __syncthreads();
    int w = t >> 6, l = t & 63;
    int lane16 = l & 15, quad = l >> 4;
    int mrow = 16 * w + lane16;
    f32x4 acc0 = {0.f, 0.f, 0.f, 0.f}, acc1 = {0.f, 0.f, 0.f, 0.f};
#pragma unroll
    for (int kk = 0; kk < 2; ++kk) {
        int k0 = kk * 32 + quad * 8;
        bf16x8 a  = *(const bf16x8*)&ab[mrow][k0];
        bf16x8 b0 = *(const bf16x8*)&wb[lane16][k0];
        bf16x8 b1 = *(const bf16x8*)&wb[lane16 + 16][k0];
        acc0 = __builtin_amdgcn_mfma_f32_16x16x32_bf16(a, b0, acc0, 0, 0, 0);
        acc1 = __builtin_amdgcn_mfma_f32_16x16x32_bf16(a, b1, acc1, 0, 0, 0);
    }
    __syncthreads();
    int orow = 16 * w + quad * 4;
    float d0 = dinv[min(rbase + orow + 0, N - 1)];
    float d1 = dinv[min(rbase + orow + 1, N - 1)];
    float d2 = dinv[min(rbase + orow + 2, N - 1)];
    float d3 = dinv[min(rbase + orow + 3, N - 1)];
    ab[orow + 0][lane16]      = (ushort_t)f2bf(acc0.x * d0);
    ab[orow + 1][lane16]      = (ushort_t)f2bf(acc0.y * d1);
    ab[orow + 2][lane16]      = (ushort_t)f2bf(acc0.z * d2);
    ab[orow + 3][lane16]      = (ushort_t)f2bf(acc0.w * d3);
    ab[orow + 0][lane16 + 16] = (ushort_t)f2bf(acc1.x * d0);
    ab[orow + 1][lane16 + 16] = (ushort_t)f2bf(acc1.y * d1);
    ab[orow + 2][lane16 + 16] = (ushort_t)f2bf(acc1.z * d2);
    ab[orow + 3][lane16 + 16] = (ushort_t)f2bf(acc1.w * d3);
    __syncthreads();
    for (int i = t; i < 256; i += BLK) {
        int r = i >> 2, c4 = i & 3;
        int rr = rbase + r;
        if (rr < N) {
            uint4 v = *(const uint4*)&ab[r][8 * c4];
            *(uint4*)&hs2[(size_t)rr * 32 + 8 * c4] = v;
        }
    }
}

// ---- layer 2 aggregation: 16 groups x 4 lanes; same csr-preload + shfl
// broadcast structure; pk_add accumulate (hs2 pre-scaled).
__global__ void k_agg2(const uint_t* __restrict__ hs2, const int* __restrict__ row_ptr,
                       const int* __restrict__ deg, const int* __restrict__ csr_src,
                       const float* __restrict__ dinv, const float* __restrict__ b2,
                       float* __restrict__ out, int N) {
    int node = (blockIdx.x * blockDim.x + threadIdx.x) >> 6;
    if (node >= N) return;
    int lane = threadIdx.x & 63;
    int g = lane >> 2;   // edge slot 0..15
    int c = lane & 3;    // uint4 column: features [8c, 8c+8)
    const uint4* H = (const uint4*)hs2;
    v2f a0 = {0.f, 0.f}, a1_ = {0.f, 0.f}, a2 = {0.f, 0.f}, a3 = {0.f, 0.f};
    int beg = row_ptr[node], tot = deg[node];
    int jal = (lane < tot) ? csr_src[beg + lane] : 0;   // one coalesced load
    if (g == 0) pkadd(a0, a1_, a2, a3, H[(size_t)node * 4 + c]);  // self-loop
    int nt = (tot + 15) >> 4;
    int t = 0;
    for (; t + 1 < nt; t += 2) {
        int s0 = g + 16 * t, s1 = s0 + 16;    // s0 < tot guaranteed here
        int j0 = __shfl(jal, s0 & 63, 64);
        int j1 = __shfl(jal, s1 & 63, 64);
        if (s0 >= 64) j0 = csr_src[beg + s0];
        bool p1 = s1 < tot;
        if (s1 >= 64 && p1) j1 = csr_src[beg + s1];
        uint4 v0 = H[(size_t)j0 * 4 + c];
        uint4 v1;
        if (p1) v1 = H[(size_t)j1 * 4 + c];
        pkadd(a0, a1_, a2, a3, v0);
        if (p1) pkadd(a0, a1_, a2, a3, v1);
    }
    for (; t < nt; ++t) {
        int s = g + 16 * t;
        int j = __shfl(jal, s & 63, 64);
        bool p = s < tot;
        if (s >= 64 && p) j = csr_src[beg + s];
        if (p) pkadd(a0, a1_, a2, a3, H[(size_t)j * 4 + c]);
    }
#pragma unroll
    for (int m = 4; m <= 32; m <<= 1) {
        a0.x += __shfl_xor(a0.x, m, 64); a0.y += __shfl_xor(a0.y, m, 64);
        a1_.x += __shfl_xor(a1_.x, m, 64); a1_.y += __shfl_xor(a1_.y, m, 64);
        a2.x += __shfl_xor(a2.x, m, 64); a2.y += __shfl_xor(a2.y, m, 64);
        a3.x += __shfl_xor(a3.x, m, 64); a3.y += __shfl_xor(a3.y, m, 64);
    }
    if (g == 0) {
        float s = dinv[node];
        const float4* B = (const float4*)b2;
        float4 bv0 = B[2 * c], bv1 = B[2 * c + 1];
        float4 o0, o1;
        o0.x = fmaf(a0.x, s, bv0.x);
        o0.y = fmaf(a0.y, s, bv0.y);
        o0.z = fmaf(a1_.x, s, bv0.z);
        o0.w = fmaf(a1_.y, s, bv0.w);
        o1.x = fmaf(a2.x, s, bv1.x);
        o1.y = fmaf(a2.y, s, bv1.y);
        o1.z = fmaf(a3.x, s, bv1.z);
        o1.w = fmaf(a3.y, s, bv1.w);
        float4* O = (float4*)out;
        O[(size_t)node * 8 + 2 * c] = o0;
        O[(size_t)node * 8 + 2 * c + 1] = o1;
    }
}

extern "C" void kernel_launch(void* const* d_in, const int* in_sizes, int n_in,
                              void* d_out, int out_size, void* d_ws, size_t ws_size,
                              hipStream_t stream) {
    const float* x  = (const float*)d_in[0];
    const int*   idx = (const int*)d_in[1];
    const float* W1 = (const float*)d_in[2];
    const float* b1 = (const float*)d_in[3];
    const float* W2 = (const float*)d_in[4];
    const float* b2 = (const float*)d_in[5];
    float* out = (float*)d_out;

    const int N = in_sizes[0] / 128;   // 100000 (< 2^17, required by packing)
    const int E = in_sizes[1] / 2;     // 1600000
    const int nbuck = (N + NPB - 1) >> BSHIFT;        // 98 (<= NBMAX)
    const int PB = (E + BLK * EPT - 1) / (BLK * EPT); // 782

    // workspace layout (256B aligned)
    char* ws = (char*)d_ws;
    size_t off = 0;
    auto alloc = [&](size_t bytes) -> char* {
        char* p = ws + off;
        off = (off + bytes + 255) & ~(size_t)255;
        return p;
    };
    float* dinv     = (float*)alloc((size_t)N * 4);
    int*   row_ptr  = (int*)alloc((size_t)N * 4);
    int*   deg      = (int*)alloc((size_t)N * 4);
    int*   bcursor  = (int*)alloc((size_t)nbuck * 4);
    int*   csr_src  = (int*)alloc((size_t)nbuck * SLOTB * 4);   // 7.2 MB
    size_t ep_bytes = (size_t)nbuck * SLOTB * 4;                // 7.2 MB
    size_t h1_bytes = (size_t)N * 64 * 2;                       // 12.8 MB
    int*   edge_part = (int*)alloc(ep_bytes > h1_bytes ? ep_bytes : h1_bytes);
    ushort_t* a1b   = (ushort_t*)alloc((size_t)N * 64 * 2);
    ushort_t* hs1   = (ushort_t*)edge_part;   // alias: edge_part dead after k_csr
    ushort_t* hs2   = hs1;                    // alias: hs1 dead after k_agg1

    hipMemsetAsync(bcursor, 0, (size_t)nbuck * 4, stream);
    k_part<<<PB, BLK, 0, stream>>>(idx, bcursor, edge_part, E, nbuck);
    k_csr<<<nbuck, BLKC, 0, stream>>>(edge_part, bcursor, row_ptr, deg, dinv,
                                      csr_src, N, nbuck);
    k_gemm1<<<(N + 63) / 64, BLK, 0, stream>>>(x, W1, dinv, hs1, N);
    k_agg1<<<(N + 3) / 4, BLK, 0, stream>>>((const uint_t*)hs1, row_ptr, deg,
                                            csr_src, dinv, b1, a1b, N);
    k_gemm2<<<(N + 63) / 64, BLK, 0, stream>>>(a1b, W2, dinv, hs2, N);
    k_agg2<<<(N + 3) / 4, BLK, 0, stream>>>((const uint_t*)hs2, row_ptr, deg,
                                            csr_src, dinv, b2, out, N);
}

// Round 2
// 229.718 us; speedup vs baseline: 1.1349x; 1.0895x over previous
//
#include <hip/hip_runtime.h>

// GCN 2-layer: x[N,128] -> GCNConv(W1[128,64], b1) -> ReLU -> GCNConv(W2[64,32], b2)
// norm = dinv[src]*dinv[dst] factorized. Bucketed multisplit build (R4), bf16
// intermediates (R5), MFMA gemms (R8), dense per-bucket edge segments (R10),
// pre-scaled hs (R11).
// R12: aggs restructured wave-per-node -> GROUP-per-node (agg1: 8 lanes/node,
// 8 nodes/wave; agg2: 4 lanes/node, 16 nodes/wave). Each lane accumulates its
// own feature slice across all of its node's edges: the 48-64-instr cross-lane
// reduce is GONE and the epilogue runs at full lane utilization (R11 counters:
// VALUBusy 60%, HBM 29% -> VALU-issue-bound; reduce+serial epilogue were ~50%
// of the per-node instruction budget). Loop runs to wave-max degree
// (E[max8 Poisson(16)]~23, ~71% predication efficiency - cheap vs the win).

#define BLK 256
#define BLKC 1024        // k_csr block size
#define EPT 8            // edges/thread in k_part
#define BSHIFT 10        // nodes per bucket
#define NPB 1024         // 1 << BSHIFT
#define SLOTB 18432      // edge slots per bucket; lambda~16.3K, 16 sigma
#define NBMAX 128        // >= nbuck = ceil(N/NPB) = 98

typedef unsigned int uint_t;
typedef unsigned short ushort_t;
typedef __attribute__((ext_vector_type(2))) float v2f;      // v_pk_* pair
typedef __attribute__((ext_vector_type(8))) short bf16x8;   // MFMA A/B frag
typedef __attribute__((ext_vector_type(4))) float f32x4;    // MFMA C/D frag

__device__ __forceinline__ uint_t f2bf(float x) {   // RNE float->bf16 (low 16)
    union { float f; uint_t u; } un; un.f = x;
    uint_t u = un.u;
    return (u + 0x7fffu + ((u >> 16) & 1u)) >> 16;
}

// 8 bf16 (uint4) += into 4 float2 accumulators (v_pk_add_f32 path)
__device__ __forceinline__ void pkadd(v2f& a0, v2f& a1, v2f& a2, v2f& a3, uint4 v) {
    v2f p;
    p.x = __uint_as_float(v.x << 16); p.y = __uint_as_float(v.x & 0xffff0000u); a0 += p;
    p.x = __uint_as_float(v.y << 16); p.y = __uint_as_float(v.y & 0xffff0000u); a1 += p;
    p.x = __uint_as_float(v.z << 16); p.y = __uint_as_float(v.z & 0xffff0000u); a2 += p;
    p.x = __uint_as_float(v.w << 16); p.y = __uint_as_float(v.w & 0xffff0000u); a3 += p;
}

// int64-layout detection (wave-uniform, L2-hot)
__device__ __forceinline__ bool detect64(const int* __restrict__ idx) {
    int z = 0;
#pragma unroll
    for (int i = 1; i < 32; i += 2) z |= idx[i];
    return z == 0;
}

// ---- build pass 1: partition edges into DENSE per-bucket segments.
__global__ void k_part(const int* __restrict__ idx, int* __restrict__ bcursor,
                       int* __restrict__ edge_part, int E, int nbuck) {
    __shared__ int h[NBMAX];
    __shared__ int rb[NBMAX];
    bool is64 = detect64(idx);
    int t = threadIdx.x, blk = blockIdx.x;
    for (int i = t; i < nbuck; i += BLK) h[i] = 0;
    __syncthreads();
    int base = blk * (BLK * EPT) + t;
    int dst[EPT], src[EPT];
#pragma unroll
    for (int k = 0; k < EPT; ++k) {
        int e = base + k * BLK;
        if (e < E) {
            dst[k] = is64 ? idx[2 * (E + e)] : idx[E + e];
            src[k] = is64 ? idx[2 * e] : idx[e];
            atomicAdd(&h[dst[k] >> BSHIFT], 1);
        } else {
            dst[k] = -1;
        }
    }
    __syncthreads();
    for (int i = t; i < nbuck; i += BLK) {
        int c = h[i];
        rb[i] = c ? atomicAdd(&bcursor[i], c) : 0;
        h[i] = 0;
    }
    __syncthreads();
#pragma unroll
    for (int k = 0; k < EPT; ++k) {
        if (dst[k] >= 0) {
            int b = dst[k] >> BSHIFT;
            int r = atomicAdd(&h[b], 1);
            edge_part[(size_t)b * SLOTB + rb[b] + r] =
                src[k] | ((dst[k] & (NPB - 1)) << 17);
        }
    }
}

// ---- build pass 2: one 1024-thread block per bucket; emits row_ptr, deg,
// dinv, csr_src.
__global__ __launch_bounds__(BLKC) void k_csr(
        const int* __restrict__ edge_part, const int* __restrict__ bcursor,
        int* __restrict__ row_ptr, int* __restrict__ deg, float* __restrict__ dinv,
        int* __restrict__ csr_src, int N, int nbuck) {
    __shared__ int cnt[NPB];
    __shared__ int off[NPB];
    int b = blockIdx.x, t = threadIdx.x;
    int node0 = b << BSHIFT;
    int nn = min(NPB, N - node0);
    int m = bcursor[b];                   // total edges in this bucket
    size_t ebase = (size_t)b * SLOTB;
    cnt[t] = 0;
    __syncthreads();
    for (int e = t; e < m; e += BLKC)
        atomicAdd(&cnt[((unsigned)edge_part[ebase + e]) >> 17], 1);
    __syncthreads();
    // inclusive scan of cnt[1024] (1 entry/thread) -> exclusive offsets
    off[t] = cnt[t];
    __syncthreads();
    for (int st = 1; st < BLKC; st <<= 1) {
        int v = (t >= st) ? off[t - st] : 0;
        __syncthreads();
        off[t] += v;
        __syncthreads();
    }
    int excl = off[t] - cnt[t];
    off[t] = excl;                        // own-entry overwrite, no cross-read
    if (t < nn) {
        row_ptr[node0 + t] = (int)(ebase + excl);
        deg[node0 + t] = cnt[t];
        dinv[node0 + t] = rsqrtf((float)(cnt[t] + 1));  // +1 self-loop
    }
    __syncthreads();
    for (int e = t; e < m; e += BLKC) {
        int p = edge_part[ebase + e];
        int dlo = ((unsigned)p) >> 17;
        int r = atomicAdd(&off[dlo], 1);
        csr_src[ebase + r] = p & 0x1FFFF;
    }
}

// ---- layer 1 GEMM (MFMA bf16): 64 rows x 64 cols per block, 4 waves.
// hs1[i,f] = bf16((x @ W1)[i,f] * dinv[i])  -- PRE-SCALED (agg1 adds directly).
__global__ __launch_bounds__(256) void k_gemm1(
        const float* __restrict__ x, const float* __restrict__ W1,
        const float* __restrict__ dinv, ushort_t* __restrict__ hs1, int N) {
    __shared__ ushort_t xb[64][136];   // x tile, bf16 (+pad -> frag reads <=2-way)
    __shared__ ushort_t wb[64][136];   // W1 transposed (wb[n][k]), bf16
    int t = threadIdx.x;
    int rbase = blockIdx.x * 64;
    for (int i = t; i < 2048; i += BLK) {
        int k = i >> 4, n4 = i & 15;
        float4 w = ((const float4*)W1)[i];
        wb[4 * n4 + 0][k] = (ushort_t)f2bf(w.x);
        wb[4 * n4 + 1][k] = (ushort_t)f2bf(w.y);
        wb[4 * n4 + 2][k] = (ushort_t)f2bf(w.z);
        wb[4 * n4 + 3][k] = (ushort_t)f2bf(w.w);
    }
    for (int i = t; i < 2048; i += BLK) {
        int r = i >> 5, c4 = i & 31;
        int rr = rbase + r; if (rr >= N) rr = N - 1;
        float4 v = ((const float4*)x)[(size_t)rr * 32 + c4];
        uint2 p;
        p.x = f2bf(v.x) | (f2bf(v.y) << 16);
        p.y = f2bf(v.z) | (f2bf(v.w) << 16);
        *(uint2*)&xb[r][4 * c4] = p;
    }
    __syncthreads();
    int w = t >> 6, l = t & 63;
    int lane16 = l & 15, quad = l >> 4;
    int mrow = 16 * w + lane16;
    f32x4 acc0 = {0.f, 0.f, 0.f, 0.f}, acc1 = {0.f, 0.f, 0.f, 0.f};
    f32x4 acc2 = {0.f, 0.f, 0.f, 0.f}, acc3 = {0.f, 0.f, 0.f, 0.f};
#pragma unroll
    for (int kk = 0; kk < 4; ++kk) {
        int k0 = kk * 32 + quad * 8;
        bf16x8 a  = *(const bf16x8*)&xb[mrow][k0];
        bf16x8 b0 = *(const bf16x8*)&wb[lane16][k0];
        bf16x8 b1 = *(const bf16x8*)&wb[lane16 + 16][k0];
        bf16x8 b2 = *(const bf16x8*)&wb[lane16 + 32][k0];
        bf16x8 b3 = *(const bf16x8*)&wb[lane16 + 48][k0];
        acc0 = __builtin_amdgcn_mfma_f32_16x16x32_bf16(a, b0, acc0, 0, 0, 0);
        acc1 = __builtin_amdgcn_mfma_f32_16x16x32_bf16(a, b1, acc1, 0, 0, 0);
        acc2 = __builtin_amdgcn_mfma_f32_16x16x32_bf16(a, b2, acc2, 0, 0, 0);
        acc3 = __builtin_amdgcn_mfma_f32_16x16x32_bf16(a, b3, acc3, 0, 0, 0);
    }
    __syncthreads();
    int orow = 16 * w + quad * 4;   // D: row = quad*4+reg, col = lane16 (+16c)
    float d0 = dinv[min(rbase + orow + 0, N - 1)];
    float d1 = dinv[min(rbase + orow + 1, N - 1)];
    float d2 = dinv[min(rbase + orow + 2, N - 1)];
    float d3 = dinv[min(rbase + orow + 3, N - 1)];
    xb[orow + 0][lane16]      = (ushort_t)f2bf(acc0.x * d0);
    xb[orow + 1][lane16]      = (ushort_t)f2bf(acc0.y * d1);
    xb[orow + 2][lane16]      = (ushort_t)f2bf(acc0.z * d2);
    xb[orow + 3][lane16]      = (ushort_t)f2bf(acc0.w * d3);
    xb[orow + 0][lane16 + 16] = (ushort_t)f2bf(acc1.x * d0);
    xb[orow + 1][lane16 + 16] = (ushort_t)f2bf(acc1.y * d1);
    xb[orow + 2][lane16 + 16] = (ushort_t)f2bf(acc1.z * d2);
    xb[orow + 3][lane16 + 16] = (ushort_t)f2bf(acc1.w * d3);
    xb[orow + 0][lane16 + 32] = (ushort_t)f2bf(acc2.x * d0);
    xb[orow + 1][lane16 + 32] = (ushort_t)f2bf(acc2.y * d1);
    xb[orow + 2][lane16 + 32] = (ushort_t)f2bf(acc2.z * d2);
    xb[orow + 3][lane16 + 32] = (ushort_t)f2bf(acc2.w * d3);
    xb[orow + 0][lane16 + 48] = (ushort_t)f2bf(acc3.x * d0);
    xb[orow + 1][lane16 + 48] = (ushort_t)f2bf(acc3.y * d1);
    xb[orow + 2][lane16 + 48] = (ushort_t)f2bf(acc3.z * d2);
    xb[orow + 3][lane16 + 48] = (ushort_t)f2bf(acc3.w * d3);
    __syncthreads();
    for (int i = t; i < 512; i += BLK) {
        int r = i >> 3, c8 = i & 7;
        int rr = rbase + r;
        if (rr < N) {
            uint4 v = *(const uint4*)&xb[r][8 * c8];
            *(uint4*)&hs1[(size_t)rr * 64 + 8 * c8] = v;
        }
    }
}

// ---- layer 1 aggregation: 8 lanes per node (8 x uint4 = full 128B row),
// 8 nodes per wave. Per-lane accumulation over ALL of its node's edges ->
// no cross-lane reduce, full-width epilogue. csr chunk-preload (8 coalesced
// ints per group) + intra-group __shfl broadcast.
__global__ void k_agg1(const uint_t* __restrict__ hs1, const int* __restrict__ row_ptr,
                       const int* __restrict__ deg, const int* __restrict__ csr_src,
                       const float* __restrict__ dinv, const float* __restrict__ b1,
                       ushort_t* __restrict__ a1b, int N) {
    int lane = threadIdx.x & 63;
    int g = lane >> 3;   // node sub-index within wave (0..7)
    int c = lane & 7;    // uint4 column: features [8c, 8c+8)
    int wavebase = ((blockIdx.x * blockDim.x + threadIdx.x) >> 6) * 8;
    int node = wavebase + g;
    bool alive = node < N;
    int nodeC = alive ? node : N - 1;
    const uint4* H = (const uint4*)hs1;
    v2f a0 = {0.f, 0.f}, a1_ = {0.f, 0.f}, a2 = {0.f, 0.f}, a3 = {0.f, 0.f};
    float dn = dinv[nodeC];
    int beg = row_ptr[nodeC];
    int tot = alive ? deg[nodeC] : 0;
    // self-loop (pre-scaled hs1 -> plain add; the dn^2 factor lands via dn*...)
    pkadd(a0, a1_, a2, a3, H[(size_t)nodeC * 8 + c]);
    int gbase = lane & 0x38;             // first lane of this group
    for (int eb = 0; __any(eb < tot); eb += 8) {
        int jal = 0;
        if (eb + c < tot) jal = csr_src[beg + eb + c];   // coalesced 8/group
#pragma unroll
        for (int e = 0; e < 8; ++e) {
            int j = __shfl(jal, gbase + e, 64);
            if (eb + e < tot) pkadd(a0, a1_, a2, a3, H[(size_t)j * 8 + c]);
        }
    }
    if (alive) {
        const float4* B = (const float4*)b1;
        float4 bv0 = B[2 * c], bv1 = B[2 * c + 1];
        float o0 = fmaxf(fmaf(a0.x, dn, bv0.x), 0.f);
        float o1 = fmaxf(fmaf(a0.y, dn, bv0.y), 0.f);
        float o2 = fmaxf(fmaf(a1_.x, dn, bv0.z), 0.f);
        float o3 = fmaxf(fmaf(a1_.y, dn, bv0.w), 0.f);
        float o4 = fmaxf(fmaf(a2.x, dn, bv1.x), 0.f);
        float o5 = fmaxf(fmaf(a2.y, dn, bv1.y), 0.f);
        float o6 = fmaxf(fmaf(a3.x, dn, bv1.z), 0.f);
        float o7 = fmaxf(fmaf(a3.y, dn, bv1.w), 0.f);
        uint4 o;
        o.x = f2bf(o0) | (f2bf(o1) << 16);
        o.y = f2bf(o2) | (f2bf(o3) << 16);
        o.z = f2bf(o4) | (f2bf(o5) << 16);
        o.w = f2bf(o6) | (f2bf(o7) << 16);
        ((uint4*)a1b)[(size_t)node * 8 + c] = o;   // wave writes 1KB contiguous
    }
}

// ---- layer 2 GEMM (MFMA bf16): 64 rows x 32 cols per block, 4 waves.
// hs2[i,f] = bf16((a1 @ W2)[i,f] * dinv[i])  -- pre-scaled (agg2 adds directly).
__global__ __launch_bounds__(256) void k_gemm2(
        const ushort_t* __restrict__ a1b, const float* __restrict__ W2,
        const float* __restrict__ dinv, ushort_t* __restrict__ hs2, int N) {
    __shared__ ushort_t ab[64][72];
    __shared__ ushort_t wb[32][72];
    int t = threadIdx.x;
    int rbase = blockIdx.x * 64;
    for (int i = t; i < 512; i += BLK) {
        int k = i >> 3, n4 = i & 7;
        float4 w = ((const float4*)W2)[i];
        wb[4 * n4 + 0][k] = (ushort_t)f2bf(w.x);
        wb[4 * n4 + 1][k] = (ushort_t)f2bf(w.y);
        wb[4 * n4 + 2][k] = (ushort_t)f2bf(w.z);
        wb[4 * n4 + 3][k] = (ushort_t)f2bf(w.w);
    }
    for (int i = t; i < 512; i += BLK) {
        int r = i >> 3, c8 = i & 7;
        int rr = rbase + r; if (rr >= N) rr = N - 1;
        uint4 v = ((const uint4*)a1b)[(size_t)rr * 8 + c8];
        *(uint4*)&ab[r][8 * c8] = v;
    }
    __syncthreads();
    int w = t >> 6, l = t & 63;
    int lane16 = l & 15, quad = l >> 4;
    int mrow = 16 * w + lane16;
    f32x4 acc0 = {0.f, 0.f, 0.f, 0.f}, acc1 = {0.f, 0.f, 0.f, 0.f};
#pragma unroll
    for (int kk = 0; kk < 2; ++kk) {
        int k0 = kk * 32 + quad * 8;
        bf16x8 a  = *(const bf16x8*)&ab[mrow][k0];
        bf16x8 b0 = *(const bf16x8*)&wb[lane16][k0];
        bf16x8 b1 = *(const bf16x8*)&wb[lane16 + 16][k0];
        acc0 = __builtin_amdgcn_mfma_f32_16x16x32_bf16(a, b0, acc0, 0, 0, 0);
        acc1 = __builtin_amdgcn_mfma_f32_16x16x32_bf16(a, b1, acc1, 0, 0, 0);
    }
    __syncthreads();
    int orow = 16 * w + quad * 4;
    float d0 = dinv[min(rbase + orow + 0, N - 1)];
    float d1 = dinv[min(rbase + orow + 1, N - 1)];
    float d2 = dinv[min(rbase + orow + 2, N - 1)];
    float d3 = dinv[min(rbase + orow + 3, N - 1)];
    ab[orow + 0][lane16]      = (ushort_t)f2bf(acc0.x * d0);
    ab[orow + 1][lane16]      = (ushort_t)f2bf(acc0.y * d1);
    ab[orow + 2][lane16]      = (ushort_t)f2bf(acc0.z * d2);
    ab[orow + 3][lane16]      = (ushort_t)f2bf(acc0.w * d3);
    ab[orow + 0][lane16 + 16] = (ushort_t)f2bf(acc1.x * d0);
    ab[orow + 1][lane16 + 16] = (ushort_t)f2bf(acc1.y * d1);
    ab[orow + 2][lane16 + 16] = (ushort_t)f2bf(acc1.z * d2);
    ab[orow + 3][lane16 + 16] = (ushort_t)f2bf(acc1.w * d3);
    __syncthreads();
    for (int i = t; i < 256; i += BLK) {
        int r = i >> 2, c4 = i & 3;
        int rr = rbase + r;
        if (rr < N) {
            uint4 v = *(const uint4*)&ab[r][8 * c4];
            *(uint4*)&hs2[(size_t)rr * 32 + 8 * c4] = v;
        }
    }
}

// ---- layer 2 aggregation: 4 lanes per node (4 x uint4 = full 64B row),
// 16 nodes per wave; same group-per-node structure, pk_add accumulate.
__global__ void k_agg2(const uint_t* __restrict__ hs2, const int* __restrict__ row_ptr,
                       const int* __restrict__ deg, const int* __restrict__ csr_src,
                       const float* __restrict__ dinv, const float* __restrict__ b2,
                       float* __restrict__ out, int N) {
    int lane = threadIdx.x & 63;
    int g = lane >> 2;   // node sub-index within wave (0..15)
    int c = lane & 3;    // uint4 column: features [8c, 8c+8)
    int wavebase = ((blockIdx.x * blockDim.x + threadIdx.x) >> 6) * 16;
    int node = wavebase + g;
    bool alive = node < N;
    int nodeC = alive ? node : N - 1;
    const uint4* H = (const uint4*)hs2;
    v2f a0 = {0.f, 0.f}, a1_ = {0.f, 0.f}, a2 = {0.f, 0.f}, a3 = {0.f, 0.f};
    float dn = dinv[nodeC];
    int beg = row_ptr[nodeC];
    int tot = alive ? deg[nodeC] : 0;
    pkadd(a0, a1_, a2, a3, H[(size_t)nodeC * 4 + c]);   // self-loop
    int gbase = lane & 0x3C;             // first lane of this group
    for (int eb = 0; __any(eb < tot); eb += 4) {
        int jal = 0;
        if (eb + c < tot) jal = csr_src[beg + eb + c];   // coalesced 4/group
#pragma unroll
        for (int e = 0; e < 4; ++e) {
            int j = __shfl(jal, gbase + e, 64);
            if (eb + e < tot) pkadd(a0, a1_, a2, a3, H[(size_t)j * 4 + c]);
        }
    }
    if (alive) {
        const float4* B = (const float4*)b2;
        float4 bv0 = B[2 * c], bv1 = B[2 * c + 1];
        float4 o0, o1;
        o0.x = fmaf(a0.x, dn, bv0.x);
        o0.y = fmaf(a0.y, dn, bv0.y);
        o0.z = fmaf(a1_.x, dn, bv0.z);
        o0.w = fmaf(a1_.y, dn, bv0.w);
        o1.x = fmaf(a2.x, dn, bv1.x);
        o1.y = fmaf(a2.y, dn, bv1.y);
        o1.z = fmaf(a3.x, dn, bv1.z);
        o1.w = fmaf(a3.y, dn, bv1.w);
        float4* O = (float4*)out;
        O[(size_t)node * 8 + 2 * c] = o0;
        O[(size_t)node * 8 + 2 * c + 1] = o1;
    }
}

extern "C" void kernel_launch(void* const* d_in, const int* in_sizes, int n_in,
                              void* d_out, int out_size, void* d_ws, size_t ws_size,
                              hipStream_t stream) {
    const float* x  = (const float*)d_in[0];
    const int*   idx = (const int*)d_in[1];
    const float* W1 = (const float*)d_in[2];
    const float* b1 = (const float*)d_in[3];
    const float* W2 = (const float*)d_in[4];
    const float* b2 = (const float*)d_in[5];
    float* out = (float*)d_out;

    const int N = in_sizes[0] / 128;   // 100000 (< 2^17, required by packing)
    const int E = in_sizes[1] / 2;     // 1600000
    const int nbuck = (N + NPB - 1) >> BSHIFT;        // 98 (<= NBMAX)
    const int PB = (E + BLK * EPT - 1) / (BLK * EPT); // 782

    // workspace layout (256B aligned)
    char* ws = (char*)d_ws;
    size_t off = 0;
    auto alloc = [&](size_t bytes) -> char* {
        char* p = ws + off;
        off = (off + bytes + 255) & ~(size_t)255;
        return p;
    };
    float* dinv     = (float*)alloc((size_t)N * 4);
    int*   row_ptr  = (int*)alloc((size_t)N * 4);
    int*   deg      = (int*)alloc((size_t)N * 4);
    int*   bcursor  = (int*)alloc((size_t)nbuck * 4);
    int*   csr_src  = (int*)alloc((size_t)nbuck * SLOTB * 4);   // 7.2 MB
    size_t ep_bytes = (size_t)nbuck * SLOTB * 4;                // 7.2 MB
    size_t h1_bytes = (size_t)N * 64 * 2;                       // 12.8 MB
    int*   edge_part = (int*)alloc(ep_bytes > h1_bytes ? ep_bytes : h1_bytes);
    ushort_t* a1b   = (ushort_t*)alloc((size_t)N * 64 * 2);
    ushort_t* hs1   = (ushort_t*)edge_part;   // alias: edge_part dead after k_csr
    ushort_t* hs2   = hs1;                    // alias: hs1 dead after k_agg1

    hipMemsetAsync(bcursor, 0, (size_t)nbuck * 4, stream);
    k_part<<<PB, BLK, 0, stream>>>(idx, bcursor, edge_part, E, nbuck);
    k_csr<<<nbuck, BLKC, 0, stream>>>(edge_part, bcursor, row_ptr, deg, dinv,
                                      csr_src, N, nbuck);
    k_gemm1<<<(N + 63) / 64, BLK, 0, stream>>>(x, W1, dinv, hs1, N);
    k_agg1<<<(N * 8 + BLK - 1) / BLK / 4 * 4 + 4, BLK, 0, stream>>>(
        (const uint_t*)hs1, row_ptr, deg, csr_src, dinv, b1, a1b, N);
    k_gemm2<<<(N + 63) / 64, BLK, 0, stream>>>(a1b, W2, dinv, hs2, N);
    k_agg2<<<(N * 4 + BLK - 1) / BLK, BLK, 0, stream>>>(
        (const uint_t*)hs2, row_ptr, deg, csr_src, dinv, b2, out, N);
}

// Round 3
// 220.762 us; speedup vs baseline: 1.1809x; 1.0406x over previous
//
#include <hip/hip_runtime.h>

// GCN 2-layer: x[N,128] -> GCNConv(W1[128,64], b1) -> ReLU -> GCNConv(W2[64,32], b2)
// norm = dinv[src]*dinv[dst] factorized. Bucketed multisplit build (R4), bf16
// intermediates (R5), MFMA gemms (R8), dense per-bucket edge segments (R10),
// pre-scaled hs (R11), group-per-node aggs (R12: agg1 8 lanes/node, agg2 4
// lanes/node; no cross-lane reduce, full-width epilogue).
// R13: aggs were still serial-consume per gather (R1 VGPR=20 -> compiler
// couldn't batch; each 12-op pkadd sat behind its own ~500cy L2/L3 gather).
// Split chunk loop into issue-phase (all 8 gathers -> static uint4 vv[8],
// stays in VGPRs) + consume-phase: 8 gathers in flight/wave instead of 1.
// k_part: int64 edge list read as uint2 (one 8B load/edge instead of two
// stride-8 scalars).

#define BLK 256
#define BLKC 1024        // k_csr block size
#define EPT 8            // edges/thread in k_part
#define BSHIFT 10        // nodes per bucket
#define NPB 1024         // 1 << BSHIFT
#define SLOTB 18432      // edge slots per bucket; lambda~16.3K, 16 sigma
#define NBMAX 128        // >= nbuck = ceil(N/NPB) = 98

typedef unsigned int uint_t;
typedef unsigned short ushort_t;
typedef __attribute__((ext_vector_type(2))) float v2f;      // v_pk_* pair
typedef __attribute__((ext_vector_type(8))) short bf16x8;   // MFMA A/B frag
typedef __attribute__((ext_vector_type(4))) float f32x4;    // MFMA C/D frag

__device__ __forceinline__ uint_t f2bf(float x) {   // RNE float->bf16 (low 16)
    union { float f; uint_t u; } un; un.f = x;
    uint_t u = un.u;
    return (u + 0x7fffu + ((u >> 16) & 1u)) >> 16;
}

// 8 bf16 (uint4) += into 4 float2 accumulators (v_pk_add_f32 path)
__device__ __forceinline__ void pkadd(v2f& a0, v2f& a1, v2f& a2, v2f& a3, uint4 v) {
    v2f p;
    p.x = __uint_as_float(v.x << 16); p.y = __uint_as_float(v.x & 0xffff0000u); a0 += p;
    p.x = __uint_as_float(v.y << 16); p.y = __uint_as_float(v.y & 0xffff0000u); a1 += p;
    p.x = __uint_as_float(v.z << 16); p.y = __uint_as_float(v.z & 0xffff0000u); a2 += p;
    p.x = __uint_as_float(v.w << 16); p.y = __uint_as_float(v.w & 0xffff0000u); a3 += p;
}

// int64-layout detection (wave-uniform, L2-hot)
__device__ __forceinline__ bool detect64(const int* __restrict__ idx) {
    int z = 0;
#pragma unroll
    for (int i = 1; i < 32; i += 2) z |= idx[i];
    return z == 0;
}

// ---- build pass 1: partition edges into DENSE per-bucket segments.
__global__ void k_part(const int* __restrict__ idx, int* __restrict__ bcursor,
                       int* __restrict__ edge_part, int E, int nbuck) {
    __shared__ int h[NBMAX];
    __shared__ int rb[NBMAX];
    bool is64 = detect64(idx);
    int t = threadIdx.x, blk = blockIdx.x;
    for (int i = t; i < nbuck; i += BLK) h[i] = 0;
    __syncthreads();
    int base = blk * (BLK * EPT) + t;
    int dst[EPT], src[EPT];
#pragma unroll
    for (int k = 0; k < EPT; ++k) {
        int e = base + k * BLK;
        if (e < E) {
            if (is64) {
                uint2 dv = ((const uint2*)idx)[(size_t)E + e];   // int64 dst[e]
                uint2 sv = ((const uint2*)idx)[e];               // int64 src[e]
                dst[k] = (int)dv.x;
                src[k] = (int)sv.x;
            } else {
                dst[k] = idx[E + e];
                src[k] = idx[e];
            }
            atomicAdd(&h[dst[k] >> BSHIFT], 1);
        } else {
            dst[k] = -1;
        }
    }
    __syncthreads();
    for (int i = t; i < nbuck; i += BLK) {
        int c = h[i];
        rb[i] = c ? atomicAdd(&bcursor[i], c) : 0;
        h[i] = 0;
    }
    __syncthreads();
#pragma unroll
    for (int k = 0; k < EPT; ++k) {
        if (dst[k] >= 0) {
            int b = dst[k] >> BSHIFT;
            int r = atomicAdd(&h[b], 1);
            edge_part[(size_t)b * SLOTB + rb[b] + r] =
                src[k] | ((dst[k] & (NPB - 1)) << 17);
        }
    }
}

// ---- build pass 2: one 1024-thread block per bucket; emits row_ptr, deg,
// dinv, csr_src.
__global__ __launch_bounds__(BLKC) void k_csr(
        const int* __restrict__ edge_part, const int* __restrict__ bcursor,
        int* __restrict__ row_ptr, int* __restrict__ deg, float* __restrict__ dinv,
        int* __restrict__ csr_src, int N, int nbuck) {
    __shared__ int cnt[NPB];
    __shared__ int off[NPB];
    int b = blockIdx.x, t = threadIdx.x;
    int node0 = b << BSHIFT;
    int nn = min(NPB, N - node0);
    int m = bcursor[b];                   // total edges in this bucket
    size_t ebase = (size_t)b * SLOTB;
    cnt[t] = 0;
    __syncthreads();
    for (int e = t; e < m; e += BLKC)
        atomicAdd(&cnt[((unsigned)edge_part[ebase + e]) >> 17], 1);
    __syncthreads();
    // inclusive scan of cnt[1024] (1 entry/thread) -> exclusive offsets
    off[t] = cnt[t];
    __syncthreads();
    for (int st = 1; st < BLKC; st <<= 1) {
        int v = (t >= st) ? off[t - st] : 0;
        __syncthreads();
        off[t] += v;
        __syncthreads();
    }
    int excl = off[t] - cnt[t];
    off[t] = excl;                        // own-entry overwrite, no cross-read
    if (t < nn) {
        row_ptr[node0 + t] = (int)(ebase + excl);
        deg[node0 + t] = cnt[t];
        dinv[node0 + t] = rsqrtf((float)(cnt[t] + 1));  // +1 self-loop
    }
    __syncthreads();
    for (int e = t; e < m; e += BLKC) {
        int p = edge_part[ebase + e];
        int dlo = ((unsigned)p) >> 17;
        int r = atomicAdd(&off[dlo], 1);
        csr_src[ebase + r] = p & 0x1FFFF;
    }
}

// ---- layer 1 GEMM (MFMA bf16): 64 rows x 64 cols per block, 4 waves.
// hs1[i,f] = bf16((x @ W1)[i,f] * dinv[i])  -- PRE-SCALED (agg1 adds directly).
__global__ __launch_bounds__(256) void k_gemm1(
        const float* __restrict__ x, const float* __restrict__ W1,
        const float* __restrict__ dinv, ushort_t* __restrict__ hs1, int N) {
    __shared__ ushort_t xb[64][136];   // x tile, bf16 (+pad -> frag reads <=2-way)
    __shared__ ushort_t wb[64][136];   // W1 transposed (wb[n][k]), bf16
    int t = threadIdx.x;
    int rbase = blockIdx.x * 64;
    for (int i = t; i < 2048; i += BLK) {
        int k = i >> 4, n4 = i & 15;
        float4 w = ((const float4*)W1)[i];
        wb[4 * n4 + 0][k] = (ushort_t)f2bf(w.x);
        wb[4 * n4 + 1][k] = (ushort_t)f2bf(w.y);
        wb[4 * n4 + 2][k] = (ushort_t)f2bf(w.z);
        wb[4 * n4 + 3][k] = (ushort_t)f2bf(w.w);
    }
    for (int i = t; i < 2048; i += BLK) {
        int r = i >> 5, c4 = i & 31;
        int rr = rbase + r; if (rr >= N) rr = N - 1;
        float4 v = ((const float4*)x)[(size_t)rr * 32 + c4];
        uint2 p;
        p.x = f2bf(v.x) | (f2bf(v.y) << 16);
        p.y = f2bf(v.z) | (f2bf(v.w) << 16);
        *(uint2*)&xb[r][4 * c4] = p;
    }
    __syncthreads();
    int w = t >> 6, l = t & 63;
    int lane16 = l & 15, quad = l >> 4;
    int mrow = 16 * w + lane16;
    f32x4 acc0 = {0.f, 0.f, 0.f, 0.f}, acc1 = {0.f, 0.f, 0.f, 0.f};
    f32x4 acc2 = {0.f, 0.f, 0.f, 0.f}, acc3 = {0.f, 0.f, 0.f, 0.f};
#pragma unroll
    for (int kk = 0; kk < 4; ++kk) {
        int k0 = kk * 32 + quad * 8;
        bf16x8 a  = *(const bf16x8*)&xb[mrow][k0];
        bf16x8 b0 = *(const bf16x8*)&wb[lane16][k0];
        bf16x8 b1 = *(const bf16x8*)&wb[lane16 + 16][k0];
        bf16x8 b2 = *(const bf16x8*)&wb[lane16 + 32][k0];
        bf16x8 b3 = *(const bf16x8*)&wb[lane16 + 48][k0];
        acc0 = __builtin_amdgcn_mfma_f32_16x16x32_bf16(a, b0, acc0, 0, 0, 0);
        acc1 = __builtin_amdgcn_mfma_f32_16x16x32_bf16(a, b1, acc1, 0, 0, 0);
        acc2 = __builtin_amdgcn_mfma_f32_16x16x32_bf16(a, b2, acc2, 0, 0, 0);
        acc3 = __builtin_amdgcn_mfma_f32_16x16x32_bf16(a, b3, acc3, 0, 0, 0);
    }
    __syncthreads();
    int orow = 16 * w + quad * 4;   // D: row = quad*4+reg, col = lane16 (+16c)
    float d0 = dinv[min(rbase + orow + 0, N - 1)];
    float d1 = dinv[min(rbase + orow + 1, N - 1)];
    float d2 = dinv[min(rbase + orow + 2, N - 1)];
    float d3 = dinv[min(rbase + orow + 3, N - 1)];
    xb[orow + 0][lane16]      = (ushort_t)f2bf(acc0.x * d0);
    xb[orow + 1][lane16]      = (ushort_t)f2bf(acc0.y * d1);
    xb[orow + 2][lane16]      = (ushort_t)f2bf(acc0.z * d2);
    xb[orow + 3][lane16]      = (ushort_t)f2bf(acc0.w * d3);
    xb[orow + 0][lane16 + 16] = (ushort_t)f2bf(acc1.x * d0);
    xb[orow + 1][lane16 + 16] = (ushort_t)f2bf(acc1.y * d1);
    xb[orow + 2][lane16 + 16] = (ushort_t)f2bf(acc1.z * d2);
    xb[orow + 3][lane16 + 16] = (ushort_t)f2bf(acc1.w * d3);
    xb[orow + 0][lane16 + 32] = (ushort_t)f2bf(acc2.x * d0);
    xb[orow + 1][lane16 + 32] = (ushort_t)f2bf(acc2.y * d1);
    xb[orow + 2][lane16 + 32] = (ushort_t)f2bf(acc2.z * d2);
    xb[orow + 3][lane16 + 32] = (ushort_t)f2bf(acc2.w * d3);
    xb[orow + 0][lane16 + 48] = (ushort_t)f2bf(acc3.x * d0);
    xb[orow + 1][lane16 + 48] = (ushort_t)f2bf(acc3.y * d1);
    xb[orow + 2][lane16 + 48] = (ushort_t)f2bf(acc3.z * d2);
    xb[orow + 3][lane16 + 48] = (ushort_t)f2bf(acc3.w * d3);
    __syncthreads();
    for (int i = t; i < 512; i += BLK) {
        int r = i >> 3, c8 = i & 7;
        int rr = rbase + r;
        if (rr < N) {
            uint4 v = *(const uint4*)&xb[r][8 * c8];
            *(uint4*)&hs1[(size_t)rr * 64 + 8 * c8] = v;
        }
    }
}

// ---- layer 1 aggregation: 8 lanes per node (8 x uint4 = full 128B row),
// 8 nodes per wave. R13: per chunk, ISSUE all 8 gathers into vv[8] (static
// unroll -> VGPRs), THEN consume: 8 gathers in flight per wave.
__global__ void k_agg1(const uint_t* __restrict__ hs1, const int* __restrict__ row_ptr,
                       const int* __restrict__ deg, const int* __restrict__ csr_src,
                       const float* __restrict__ dinv, const float* __restrict__ b1,
                       ushort_t* __restrict__ a1b, int N) {
    int lane = threadIdx.x & 63;
    int g = lane >> 3;   // node sub-index within wave (0..7)
    int c = lane & 7;    // uint4 column: features [8c, 8c+8)
    int wavebase = ((blockIdx.x * blockDim.x + threadIdx.x) >> 6) * 8;
    int node = wavebase + g;
    bool alive = node < N;
    int nodeC = alive ? node : N - 1;
    const uint4* H = (const uint4*)hs1;
    v2f a0 = {0.f, 0.f}, a1_ = {0.f, 0.f}, a2 = {0.f, 0.f}, a3 = {0.f, 0.f};
    float dn = dinv[nodeC];
    int beg = row_ptr[nodeC];
    int tot = alive ? deg[nodeC] : 0;
    // self-loop (pre-scaled hs1 -> plain add; the dn^2 factor lands via dn*...)
    pkadd(a0, a1_, a2, a3, H[(size_t)nodeC * 8 + c]);
    int gbase = lane & 0x38;             // first lane of this group
    for (int eb = 0; __any(eb < tot); eb += 8) {
        int jal = 0;
        if (eb + c < tot) jal = csr_src[beg + eb + c];   // coalesced 8/group
        int cnt = tot - eb;              // group-uniform remaining count
        uint4 vv[8];
#pragma unroll
        for (int e = 0; e < 8; ++e) {    // issue phase: batch the gathers
            int j = __shfl(jal, gbase + e, 64);
            if (e < cnt) vv[e] = H[(size_t)j * 8 + c];
        }
#pragma unroll
        for (int e = 0; e < 8; ++e) {    // consume phase
            if (e < cnt) pkadd(a0, a1_, a2, a3, vv[e]);
        }
    }
    if (alive) {
        const float4* B = (const float4*)b1;
        float4 bv0 = B[2 * c], bv1 = B[2 * c + 1];
        float o0 = fmaxf(fmaf(a0.x, dn, bv0.x), 0.f);
        float o1 = fmaxf(fmaf(a0.y, dn, bv0.y), 0.f);
        float o2 = fmaxf(fmaf(a1_.x, dn, bv0.z), 0.f);
        float o3 = fmaxf(fmaf(a1_.y, dn, bv0.w), 0.f);
        float o4 = fmaxf(fmaf(a2.x, dn, bv1.x), 0.f);
        float o5 = fmaxf(fmaf(a2.y, dn, bv1.y), 0.f);
        float o6 = fmaxf(fmaf(a3.x, dn, bv1.z), 0.f);
        float o7 = fmaxf(fmaf(a3.y, dn, bv1.w), 0.f);
        uint4 o;
        o.x = f2bf(o0) | (f2bf(o1) << 16);
        o.y = f2bf(o2) | (f2bf(o3) << 16);
        o.z = f2bf(o4) | (f2bf(o5) << 16);
        o.w = f2bf(o6) | (f2bf(o7) << 16);
        ((uint4*)a1b)[(size_t)node * 8 + c] = o;   // wave writes 1KB contiguous
    }
}

// ---- layer 2 GEMM (MFMA bf16): 64 rows x 32 cols per block, 4 waves.
// hs2[i,f] = bf16((a1 @ W2)[i,f] * dinv[i])  -- pre-scaled (agg2 adds directly).
__global__ __launch_bounds__(256) void k_gemm2(
        const ushort_t* __restrict__ a1b, const float* __restrict__ W2,
        const float* __restrict__ dinv, ushort_t* __restrict__ hs2, int N) {
    __shared__ ushort_t ab[64][72];
    __shared__ ushort_t wb[32][72];
    int t = threadIdx.x;
    int rbase = blockIdx.x * 64;
    for (int i = t; i < 512; i += BLK) {
        int k = i >> 3, n4 = i & 7;
        float4 w = ((const float4*)W2)[i];
        wb[4 * n4 + 0][k] = (ushort_t)f2bf(w.x);
        wb[4 * n4 + 1][k] = (ushort_t)f2bf(w.y);
        wb[4 * n4 + 2][k] = (ushort_t)f2bf(w.z);
        wb[4 * n4 + 3][k] = (ushort_t)f2bf(w.w);
    }
    for (int i = t; i < 512; i += BLK) {
        int r = i >> 3, c8 = i & 7;
        int rr = rbase + r; if (rr >= N) rr = N - 1;
        uint4 v = ((const uint4*)a1b)[(size_t)rr * 8 + c8];
        *(uint4*)&ab[r][8 * c8] = v;
    }
    __syncthreads();
    int w = t >> 6, l = t & 63;
    int lane16 = l & 15, quad = l >> 4;
    int mrow = 16 * w + lane16;
    f32x4 acc0 = {0.f, 0.f, 0.f, 0.f}, acc1 = {0.f, 0.f, 0.f, 0.f};
#pragma unroll
    for (int kk = 0; kk < 2; ++kk) {
        int k0 = kk * 32 + quad * 8;
        bf16x8 a  = *(const bf16x8*)&ab[mrow][k0];
        bf16x8 b0 = *(const bf16x8*)&wb[lane16][k0];
        bf16x8 b1 = *(const bf16x8*)&wb[lane16 + 16][k0];
        acc0 = __builtin_amdgcn_mfma_f32_16x16x32_bf16(a, b0, acc0, 0, 0, 0);
        acc1 = __builtin_amdgcn_mfma_f32_16x16x32_bf16(a, b1, acc1, 0, 0, 0);
    }
    __syncthreads();
    int orow = 16 * w + quad * 4;
    float d0 = dinv[min(rbase + orow + 0, N - 1)];
    float d1 = dinv[min(rbase + orow + 1, N - 1)];
    float d2 = dinv[min(rbase + orow + 2, N - 1)];
    float d3 = dinv[min(rbase + orow + 3, N - 1)];
    ab[orow + 0][lane16]      = (ushort_t)f2bf(acc0.x * d0);
    ab[orow + 1][lane16]      = (ushort_t)f2bf(acc0.y * d1);
    ab[orow + 2][lane16]      = (ushort_t)f2bf(acc0.z * d2);
    ab[orow + 3][lane16]      = (ushort_t)f2bf(acc0.w * d3);
    ab[orow + 0][lane16 + 16] = (ushort_t)f2bf(acc1.x * d0);
    ab[orow + 1][lane16 + 16] = (ushort_t)f2bf(acc1.y * d1);
    ab[orow + 2][lane16 + 16] = (ushort_t)f2bf(acc1.z * d2);
    ab[orow + 3][lane16 + 16] = (ushort_t)f2bf(acc1.w * d3);
    __syncthreads();
    for (int i = t; i < 256; i += BLK) {
        int r = i >> 2, c4 = i & 3;
        int rr = rbase + r;
        if (rr < N) {
            uint4 v = *(const uint4*)&ab[r][8 * c4];
            *(uint4*)&hs2[(size_t)rr * 32 + 8 * c4] = v;
        }
    }
}

// ---- layer 2 aggregation: 4 lanes per node (4 x uint4 = full 64B row),
// 16 nodes per wave; batched-issue gathers like agg1.
__global__ void k_agg2(const uint_t* __restrict__ hs2, const int* __restrict__ row_ptr,
                       const int* __restrict__ deg, const int* __restrict__ csr_src,
                       const float* __restrict__ dinv, const float* __restrict__ b2,
                       float* __restrict__ out, int N) {
    int lane = threadIdx.x & 63;
    int g = lane >> 2;   // node sub-index within wave (0..15)
    int c = lane & 3;    // uint4 column: features [8c, 8c+8)
    int wavebase = ((blockIdx.x * blockDim.x + threadIdx.x) >> 6) * 16;
    int node = wavebase + g;
    bool alive = node < N;
    int nodeC = alive ? node : N - 1;
    const uint4* H = (const uint4*)hs2;
    v2f a0 = {0.f, 0.f}, a1_ = {0.f, 0.f}, a2 = {0.f, 0.f}, a3 = {0.f, 0.f};
    float dn = dinv[nodeC];
    int beg = row_ptr[nodeC];
    int tot = alive ? deg[nodeC] : 0;
    pkadd(a0, a1_, a2, a3, H[(size_t)nodeC * 4 + c]);   // self-loop
    int gbase = lane & 0x3C;             // first lane of this group
    for (int eb = 0; __any(eb < tot); eb += 4) {
        int jal = 0;
        if (eb + c < tot) jal = csr_src[beg + eb + c];   // coalesced 4/group
        int cnt = tot - eb;
        uint4 vv[4];
#pragma unroll
        for (int e = 0; e < 4; ++e) {    // issue phase
            int j = __shfl(jal, gbase + e, 64);
            if (e < cnt) vv[e] = H[(size_t)j * 4 + c];
        }
#pragma unroll
        for (int e = 0; e < 4; ++e) {    // consume phase
            if (e < cnt) pkadd(a0, a1_, a2, a3, vv[e]);
        }
    }
    if (alive) {
        const float4* B = (const float4*)b2;
        float4 bv0 = B[2 * c], bv1 = B[2 * c + 1];
        float4 o0, o1;
        o0.x = fmaf(a0.x, dn, bv0.x);
        o0.y = fmaf(a0.y, dn, bv0.y);
        o0.z = fmaf(a1_.x, dn, bv0.z);
        o0.w = fmaf(a1_.y, dn, bv0.w);
        o1.x = fmaf(a2.x, dn, bv1.x);
        o1.y = fmaf(a2.y, dn, bv1.y);
        o1.z = fmaf(a3.x, dn, bv1.z);
        o1.w = fmaf(a3.y, dn, bv1.w);
        float4* O = (float4*)out;
        O[(size_t)node * 8 + 2 * c] = o0;
        O[(size_t)node * 8 + 2 * c + 1] = o1;
    }
}

extern "C" void kernel_launch(void* const* d_in, const int* in_sizes, int n_in,
                              void* d_out, int out_size, void* d_ws, size_t ws_size,
                              hipStream_t stream) {
    const float* x  = (const float*)d_in[0];
    const int*   idx = (const int*)d_in[1];
    const float* W1 = (const float*)d_in[2];
    const float* b1 = (const float*)d_in[3];
    const float* W2 = (const float*)d_in[4];
    const float* b2 = (const float*)d_in[5];
    float* out = (float*)d_out;

    const int N = in_sizes[0] / 128;   // 100000 (< 2^17, required by packing)
    const int E = in_sizes[1] / 2;     // 1600000
    const int nbuck = (N + NPB - 1) >> BSHIFT;        // 98 (<= NBMAX)
    const int PB = (E + BLK * EPT - 1) / (BLK * EPT); // 782

    // workspace layout (256B aligned)
    char* ws = (char*)d_ws;
    size_t off = 0;
    auto alloc = [&](size_t bytes) -> char* {
        char* p = ws + off;
        off = (off + bytes + 255) & ~(size_t)255;
        return p;
    };
    float* dinv     = (float*)alloc((size_t)N * 4);
    int*   row_ptr  = (int*)alloc((size_t)N * 4);
    int*   deg      = (int*)alloc((size_t)N * 4);
    int*   bcursor  = (int*)alloc((size_t)nbuck * 4);
    int*   csr_src  = (int*)alloc((size_t)nbuck * SLOTB * 4);   // 7.2 MB
    size_t ep_bytes = (size_t)nbuck * SLOTB * 4;                // 7.2 MB
    size_t h1_bytes = (size_t)N * 64 * 2;                       // 12.8 MB
    int*   edge_part = (int*)alloc(ep_bytes > h1_bytes ? ep_bytes : h1_bytes);
    ushort_t* a1b   = (ushort_t*)alloc((size_t)N * 64 * 2);
    ushort_t* hs1   = (ushort_t*)edge_part;   // alias: edge_part dead after k_csr
    ushort_t* hs2   = hs1;                    // alias: hs1 dead after k_agg1

    hipMemsetAsync(bcursor, 0, (size_t)nbuck * 4, stream);
    k_part<<<PB, BLK, 0, stream>>>(idx, bcursor, edge_part, E, nbuck);
    k_csr<<<nbuck, BLKC, 0, stream>>>(edge_part, bcursor, row_ptr, deg, dinv,
                                      csr_src, N, nbuck);
    k_gemm1<<<(N + 63) / 64, BLK, 0, stream>>>(x, W1, dinv, hs1, N);
    k_agg1<<<(N * 8 + BLK - 1) / BLK, BLK, 0, stream>>>(
        (const uint_t*)hs1, row_ptr, deg, csr_src, dinv, b1, a1b, N);
    k_gemm2<<<(N + 63) / 64, BLK, 0, stream>>>(a1b, W2, dinv, hs2, N);
    k_agg2<<<(N * 4 + BLK - 1) / BLK, BLK, 0, stream>>>(
        (const uint_t*)hs2, row_ptr, deg, csr_src, dinv, b2, out, N);
}

// Round 4
// 220.373 us; speedup vs baseline: 1.1830x; 1.0018x over previous
//
#include <hip/hip_runtime.h>

// GCN 2-layer: x[N,128] -> GCNConv(W1[128,64], b1) -> ReLU -> GCNConv(W2[64,32], b2)
// norm = dinv[src]*dinv[dst] factorized. Bucketed multisplit build (R4), bf16
// intermediates (R5), MFMA gemms (R8), dense per-bucket edge segments (R10),
// pre-scaled hs (R11), group-per-node aggs (R12), batched gather issue (R13).
// R14: (a) aggs get a DEPTH-2 pipeline: two named gather buffers vA/vB,
// odd/even unrolled loop ISSUE(i+1);CONSUME(i) -> chunk i's gathers stay in
// flight across chunk i+1's csr-load+shfl+issue (R13 consumed right after
// issuing: zero own-wave cover). Self-loop load hoisted, consumed last.
// Wave-uniform chunk count via shfl_xor max (no per-chunk __any).
// (b) k_part/k_csr rank capture: reuse the rank returned by the counting
// atomicAdd in the placement pass -> removes 2x1.6M LDS atomics and k_csr's
// second edge_part sweep (fixed 18-slot unrolled register arrays).

#define BLK 256
#define BLKC 1024        // k_csr block size
#define EPT 8            // edges/thread in k_part
#define CITER 18         // k_csr max edges/thread = ceil(SLOTB/BLKC)
#define BSHIFT 10        // nodes per bucket
#define NPB 1024         // 1 << BSHIFT
#define SLOTB 18432      // edge slots per bucket; lambda~16.3K, 16 sigma
#define NBMAX 128        // >= nbuck = ceil(N/NPB) = 98

typedef unsigned int uint_t;
typedef unsigned short ushort_t;
typedef __attribute__((ext_vector_type(2))) float v2f;      // v_pk_* pair
typedef __attribute__((ext_vector_type(8))) short bf16x8;   // MFMA A/B frag
typedef __attribute__((ext_vector_type(4))) float f32x4;    // MFMA C/D frag

__device__ __forceinline__ uint_t f2bf(float x) {   // RNE float->bf16 (low 16)
    union { float f; uint_t u; } un; un.f = x;
    uint_t u = un.u;
    return (u + 0x7fffu + ((u >> 16) & 1u)) >> 16;
}

// 8 bf16 (uint4) += into 4 float2 accumulators (v_pk_add_f32 path)
__device__ __forceinline__ void pkadd(v2f& a0, v2f& a1, v2f& a2, v2f& a3, uint4 v) {
    v2f p;
    p.x = __uint_as_float(v.x << 16); p.y = __uint_as_float(v.x & 0xffff0000u); a0 += p;
    p.x = __uint_as_float(v.y << 16); p.y = __uint_as_float(v.y & 0xffff0000u); a1 += p;
    p.x = __uint_as_float(v.z << 16); p.y = __uint_as_float(v.z & 0xffff0000u); a2 += p;
    p.x = __uint_as_float(v.w << 16); p.y = __uint_as_float(v.w & 0xffff0000u); a3 += p;
}

// int64-layout detection (wave-uniform, L2-hot)
__device__ __forceinline__ bool detect64(const int* __restrict__ idx) {
    int z = 0;
#pragma unroll
    for (int i = 1; i < 32; i += 2) z |= idx[i];
    return z == 0;
}

// ---- build pass 1: partition edges into DENSE per-bucket segments.
// Rank captured from the counting atomicAdd; placement pass has no atomics.
__global__ void k_part(const int* __restrict__ idx, int* __restrict__ bcursor,
                       int* __restrict__ edge_part, int E, int nbuck) {
    __shared__ int h[NBMAX];
    __shared__ int rb[NBMAX];
    bool is64 = detect64(idx);
    int t = threadIdx.x, blk = blockIdx.x;
    for (int i = t; i < nbuck; i += BLK) h[i] = 0;
    __syncthreads();
    int base = blk * (BLK * EPT) + t;
    int dst[EPT], src[EPT], rk[EPT];
#pragma unroll
    for (int k = 0; k < EPT; ++k) {
        int e = base + k * BLK;
        if (e < E) {
            if (is64) {
                uint2 dv = ((const uint2*)idx)[(size_t)E + e];   // int64 dst[e]
                uint2 sv = ((const uint2*)idx)[e];               // int64 src[e]
                dst[k] = (int)dv.x;
                src[k] = (int)sv.x;
            } else {
                dst[k] = idx[E + e];
                src[k] = idx[e];
            }
            rk[k] = atomicAdd(&h[dst[k] >> BSHIFT], 1);
        } else {
            dst[k] = -1;
        }
    }
    __syncthreads();
    for (int i = t; i < nbuck; i += BLK) {
        int c = h[i];
        rb[i] = c ? atomicAdd(&bcursor[i], c) : 0;
    }
    __syncthreads();
#pragma unroll
    for (int k = 0; k < EPT; ++k) {
        if (dst[k] >= 0) {
            int b = dst[k] >> BSHIFT;
            edge_part[(size_t)b * SLOTB + rb[b] + rk[k]] =
                src[k] | ((dst[k] & (NPB - 1)) << 17);
        }
    }
}

// ---- build pass 2: one 1024-thread block per bucket; emits row_ptr, deg,
// dinv, csr_src. Single edge sweep: payload+rank kept in fixed unrolled
// register arrays; placement pass has no atomics and no re-read.
__global__ __launch_bounds__(BLKC) void k_csr(
        const int* __restrict__ edge_part, const int* __restrict__ bcursor,
        int* __restrict__ row_ptr, int* __restrict__ deg, float* __restrict__ dinv,
        int* __restrict__ csr_src, int N, int nbuck) {
    __shared__ int cnt[NPB];
    __shared__ int off[NPB];
    int b = blockIdx.x, t = threadIdx.x;
    int node0 = b << BSHIFT;
    int nn = min(NPB, N - node0);
    int m = bcursor[b];                   // total edges in this bucket
    size_t ebase = (size_t)b * SLOTB;
    cnt[t] = 0;
    __syncthreads();
    int pp[CITER], rr[CITER];
#pragma unroll
    for (int it = 0; it < CITER; ++it) {
        int e = t + it * BLKC;
        if (e < m) {
            int p = edge_part[ebase + e];
            pp[it] = p;
            rr[it] = atomicAdd(&cnt[((unsigned)p) >> 17], 1);
        }
    }
    __syncthreads();
    // inclusive scan of cnt[1024] (1 entry/thread) -> exclusive offsets
    off[t] = cnt[t];
    __syncthreads();
    for (int st = 1; st < BLKC; st <<= 1) {
        int v = (t >= st) ? off[t - st] : 0;
        __syncthreads();
        off[t] += v;
        __syncthreads();
    }
    int excl = off[t] - cnt[t];
    off[t] = excl;                        // own-entry overwrite, no cross-read
    if (t < nn) {
        row_ptr[node0 + t] = (int)(ebase + excl);
        deg[node0 + t] = cnt[t];
        dinv[node0 + t] = rsqrtf((float)(cnt[t] + 1));  // +1 self-loop
    }
    __syncthreads();
#pragma unroll
    for (int it = 0; it < CITER; ++it) {
        int e = t + it * BLKC;
        if (e < m) {
            int p = pp[it];
            int dlo = ((unsigned)p) >> 17;
            csr_src[ebase + off[dlo] + rr[it]] = p & 0x1FFFF;
        }
    }
}

// ---- layer 1 GEMM (MFMA bf16): 64 rows x 64 cols per block, 4 waves.
// hs1[i,f] = bf16((x @ W1)[i,f] * dinv[i])  -- PRE-SCALED (agg1 adds directly).
__global__ __launch_bounds__(256) void k_gemm1(
        const float* __restrict__ x, const float* __restrict__ W1,
        const float* __restrict__ dinv, ushort_t* __restrict__ hs1, int N) {
    __shared__ ushort_t xb[64][136];   // x tile, bf16 (+pad -> frag reads <=2-way)
    __shared__ ushort_t wb[64][136];   // W1 transposed (wb[n][k]), bf16
    int t = threadIdx.x;
    int rbase = blockIdx.x * 64;
    for (int i = t; i < 2048; i += BLK) {
        int k = i >> 4, n4 = i & 15;
        float4 w = ((const float4*)W1)[i];
        wb[4 * n4 + 0][k] = (ushort_t)f2bf(w.x);
        wb[4 * n4 + 1][k] = (ushort_t)f2bf(w.y);
        wb[4 * n4 + 2][k] = (ushort_t)f2bf(w.z);
        wb[4 * n4 + 3][k] = (ushort_t)f2bf(w.w);
    }
    for (int i = t; i < 2048; i += BLK) {
        int r = i >> 5, c4 = i & 31;
        int rr = rbase + r; if (rr >= N) rr = N - 1;
        float4 v = ((const float4*)x)[(size_t)rr * 32 + c4];
        uint2 p;
        p.x = f2bf(v.x) | (f2bf(v.y) << 16);
        p.y = f2bf(v.z) | (f2bf(v.w) << 16);
        *(uint2*)&xb[r][4 * c4] = p;
    }
    __syncthreads();
    int w = t >> 6, l = t & 63;
    int lane16 = l & 15, quad = l >> 4;
    int mrow = 16 * w + lane16;
    f32x4 acc0 = {0.f, 0.f, 0.f, 0.f}, acc1 = {0.f, 0.f, 0.f, 0.f};
    f32x4 acc2 = {0.f, 0.f, 0.f, 0.f}, acc3 = {0.f, 0.f, 0.f, 0.f};
#pragma unroll
    for (int kk = 0; kk < 4; ++kk) {
        int k0 = kk * 32 + quad * 8;
        bf16x8 a  = *(const bf16x8*)&xb[mrow][k0];
        bf16x8 b0 = *(const bf16x8*)&wb[lane16][k0];
        bf16x8 b1 = *(const bf16x8*)&wb[lane16 + 16][k0];
        bf16x8 b2 = *(const bf16x8*)&wb[lane16 + 32][k0];
        bf16x8 b3 = *(const bf16x8*)&wb[lane16 + 48][k0];
        acc0 = __builtin_amdgcn_mfma_f32_16x16x32_bf16(a, b0, acc0, 0, 0, 0);
        acc1 = __builtin_amdgcn_mfma_f32_16x16x32_bf16(a, b1, acc1, 0, 0, 0);
        acc2 = __builtin_amdgcn_mfma_f32_16x16x32_bf16(a, b2, acc2, 0, 0, 0);
        acc3 = __builtin_amdgcn_mfma_f32_16x16x32_bf16(a, b3, acc3, 0, 0, 0);
    }
    __syncthreads();
    int orow = 16 * w + quad * 4;   // D: row = quad*4+reg, col = lane16 (+16c)
    float d0 = dinv[min(rbase + orow + 0, N - 1)];
    float d1 = dinv[min(rbase + orow + 1, N - 1)];
    float d2 = dinv[min(rbase + orow + 2, N - 1)];
    float d3 = dinv[min(rbase + orow + 3, N - 1)];
    xb[orow + 0][lane16]      = (ushort_t)f2bf(acc0.x * d0);
    xb[orow + 1][lane16]      = (ushort_t)f2bf(acc0.y * d1);
    xb[orow + 2][lane16]      = (ushort_t)f2bf(acc0.z * d2);
    xb[orow + 3][lane16]      = (ushort_t)f2bf(acc0.w * d3);
    xb[orow + 0][lane16 + 16] = (ushort_t)f2bf(acc1.x * d0);
    xb[orow + 1][lane16 + 16] = (ushort_t)f2bf(acc1.y * d1);
    xb[orow + 2][lane16 + 16] = (ushort_t)f2bf(acc1.z * d2);
    xb[orow + 3][lane16 + 16] = (ushort_t)f2bf(acc1.w * d3);
    xb[orow + 0][lane16 + 32] = (ushort_t)f2bf(acc2.x * d0);
    xb[orow + 1][lane16 + 32] = (ushort_t)f2bf(acc2.y * d1);
    xb[orow + 2][lane16 + 32] = (ushort_t)f2bf(acc2.z * d2);
    xb[orow + 3][lane16 + 32] = (ushort_t)f2bf(acc2.w * d3);
    xb[orow + 0][lane16 + 48] = (ushort_t)f2bf(acc3.x * d0);
    xb[orow + 1][lane16 + 48] = (ushort_t)f2bf(acc3.y * d1);
    xb[orow + 2][lane16 + 48] = (ushort_t)f2bf(acc3.z * d2);
    xb[orow + 3][lane16 + 48] = (ushort_t)f2bf(acc3.w * d3);
    __syncthreads();
    for (int i = t; i < 512; i += BLK) {
        int r = i >> 3, c8 = i & 7;
        int rr = rbase + r;
        if (rr < N) {
            uint4 v = *(const uint4*)&xb[r][8 * c8];
            *(uint4*)&hs1[(size_t)rr * 64 + 8 * c8] = v;
        }
    }
}

// ---- layer 1 aggregation: 8 lanes per node, 8 nodes per wave.
// R14: depth-2 pipeline -- ISSUE(i+1) before CONSUME(i), two named buffers.
__global__ void k_agg1(const uint_t* __restrict__ hs1, const int* __restrict__ row_ptr,
                       const int* __restrict__ deg, const int* __restrict__ csr_src,
                       const float* __restrict__ dinv, const float* __restrict__ b1,
                       ushort_t* __restrict__ a1b, int N) {
    int lane = threadIdx.x & 63;
    int g = lane >> 3;   // node sub-index within wave (0..7)
    int c = lane & 7;    // uint4 column: features [8c, 8c+8)
    int wavebase = ((blockIdx.x * blockDim.x + threadIdx.x) >> 6) * 8;
    int node = wavebase + g;
    bool alive = node < N;
    int nodeC = alive ? node : N - 1;
    const uint4* H = (const uint4*)hs1;
    float dn = dinv[nodeC];
    int beg = row_ptr[nodeC];
    int tot = alive ? deg[nodeC] : 0;
    uint4 selfv = H[(size_t)nodeC * 8 + c];   // issued early, consumed last
    int gbase = lane & 0x38;                  // first lane of this group
    // wave-uniform chunk count (max degree over the 8 nodes)
    int wtot = tot;
    wtot = max(wtot, __shfl_xor(wtot, 8, 64));
    wtot = max(wtot, __shfl_xor(wtot, 16, 64));
    wtot = max(wtot, __shfl_xor(wtot, 32, 64));
    int nch = (wtot + 7) >> 3;
    v2f a0 = {0.f, 0.f}, a1_ = {0.f, 0.f}, a2 = {0.f, 0.f}, a3 = {0.f, 0.f};
    uint4 vA[8], vB[8];
    auto ISSUE = [&](uint4 (&vv)[8], int i) {
        int base = 8 * i;
        int jal = (base + c < tot) ? csr_src[beg + base + c] : 0;
#pragma unroll
        for (int e = 0; e < 8; ++e) {
            int j = __shfl(jal, gbase + e, 64);
            if (base + e < tot) vv[e] = H[(size_t)j * 8 + c];
        }
    };
    auto CONSUME = [&](uint4 (&vv)[8], int i) {
        int base = 8 * i;
#pragma unroll
        for (int e = 0; e < 8; ++e)
            if (base + e < tot) pkadd(a0, a1_, a2, a3, vv[e]);
    };
    if (nch > 0) {
        ISSUE(vA, 0);
        int i = 1;
        for (; i + 1 < nch; i += 2) {
            ISSUE(vB, i);     CONSUME(vA, i - 1);
            ISSUE(vA, i + 1); CONSUME(vB, i);
        }
        if (i < nch) { ISSUE(vB, i); CONSUME(vA, i - 1); CONSUME(vB, i); }
        else          CONSUME(vA, i - 1);
    }
    pkadd(a0, a1_, a2, a3, selfv);            // self-loop
    if (alive) {
        const float4* B = (const float4*)b1;
        float4 bv0 = B[2 * c], bv1 = B[2 * c + 1];
        float o0 = fmaxf(fmaf(a0.x, dn, bv0.x), 0.f);
        float o1 = fmaxf(fmaf(a0.y, dn, bv0.y), 0.f);
        float o2 = fmaxf(fmaf(a1_.x, dn, bv0.z), 0.f);
        float o3 = fmaxf(fmaf(a1_.y, dn, bv0.w), 0.f);
        float o4 = fmaxf(fmaf(a2.x, dn, bv1.x), 0.f);
        float o5 = fmaxf(fmaf(a2.y, dn, bv1.y), 0.f);
        float o6 = fmaxf(fmaf(a3.x, dn, bv1.z), 0.f);
        float o7 = fmaxf(fmaf(a3.y, dn, bv1.w), 0.f);
        uint4 o;
        o.x = f2bf(o0) | (f2bf(o1) << 16);
        o.y = f2bf(o2) | (f2bf(o3) << 16);
        o.z = f2bf(o4) | (f2bf(o5) << 16);
        o.w = f2bf(o6) | (f2bf(o7) << 16);
        ((uint4*)a1b)[(size_t)node * 8 + c] = o;   // wave writes 1KB contiguous
    }
}

// ---- layer 2 GEMM (MFMA bf16): 64 rows x 32 cols per block, 4 waves.
// hs2[i,f] = bf16((a1 @ W2)[i,f] * dinv[i])  -- pre-scaled (agg2 adds directly).
__global__ __launch_bounds__(256) void k_gemm2(
        const ushort_t* __restrict__ a1b, const float* __restrict__ W2,
        const float* __restrict__ dinv, ushort_t* __restrict__ hs2, int N) {
    __shared__ ushort_t ab[64][72];
    __shared__ ushort_t wb[32][72];
    int t = threadIdx.x;
    int rbase = blockIdx.x * 64;
    for (int i = t; i < 512; i += BLK) {
        int k = i >> 3, n4 = i & 7;
        float4 w = ((const float4*)W2)[i];
        wb[4 * n4 + 0][k] = (ushort_t)f2bf(w.x);
        wb[4 * n4 + 1][k] = (ushort_t)f2bf(w.y);
        wb[4 * n4 + 2][k] = (ushort_t)f2bf(w.z);
        wb[4 * n4 + 3][k] = (ushort_t)f2bf(w.w);
    }
    for (int i = t; i < 512; i += BLK) {
        int r = i >> 3, c8 = i & 7;
        int rr = rbase + r; if (rr >= N) rr = N - 1;
        uint4 v = ((const uint4*)a1b)[(size_t)rr * 8 + c8];
        *(uint4*)&ab[r][8 * c8] = v;
    }
    __syncthreads();
    int w = t >> 6, l = t & 63;
    int lane16 = l & 15, quad = l >> 4;
    int mrow = 16 * w + lane16;
    f32x4 acc0 = {0.f, 0.f, 0.f, 0.f}, acc1 = {0.f, 0.f, 0.f, 0.f};
#pragma unroll
    for (int kk = 0; kk < 2; ++kk) {
        int k0 = kk * 32 + quad * 8;
        bf16x8 a  = *(const bf16x8*)&ab[mrow][k0];
        bf16x8 b0 = *(const bf16x8*)&wb[lane16][k0];
        bf16x8 b1 = *(const bf16x8*)&wb[lane16 + 16][k0];
        acc0 = __builtin_amdgcn_mfma_f32_16x16x32_bf16(a, b0, acc0, 0, 0, 0);
        acc1 = __builtin_amdgcn_mfma_f32_16x16x32_bf16(a, b1, acc1, 0, 0, 0);
    }
    __syncthreads();
    int orow = 16 * w + quad * 4;
    float d0 = dinv[min(rbase + orow + 0, N - 1)];
    float d1 = dinv[min(rbase + orow + 1, N - 1)];
    float d2 = dinv[min(rbase + orow + 2, N - 1)];
    float d3 = dinv[min(rbase + orow + 3, N - 1)];
    ab[orow + 0][lane16]      = (ushort_t)f2bf(acc0.x * d0);
    ab[orow + 1][lane16]      = (ushort_t)f2bf(acc0.y * d1);
    ab[orow + 2][lane16]      = (ushort_t)f2bf(acc0.z * d2);
    ab[orow + 3][lane16]      = (ushort_t)f2bf(acc0.w * d3);
    ab[orow + 0][lane16 + 16] = (ushort_t)f2bf(acc1.x * d0);
    ab[orow + 1][lane16 + 16] = (ushort_t)f2bf(acc1.y * d1);
    ab[orow + 2][lane16 + 16] = (ushort_t)f2bf(acc1.z * d2);
    ab[orow + 3][lane16 + 16] = (ushort_t)f2bf(acc1.w * d3);
    __syncthreads();
    for (int i = t; i < 256; i += BLK) {
        int r = i >> 2, c4 = i & 3;
        int rr = rbase + r;
        if (rr < N) {
            uint4 v = *(const uint4*)&ab[r][8 * c4];
            *(uint4*)&hs2[(size_t)rr * 32 + 8 * c4] = v;
        }
    }
}

// ---- layer 2 aggregation: 4 lanes per node, 16 nodes per wave; depth-2
// pipeline like agg1.
__global__ void k_agg2(const uint_t* __restrict__ hs2, const int* __restrict__ row_ptr,
                       const int* __restrict__ deg, const int* __restrict__ csr_src,
                       const float* __restrict__ dinv, const float* __restrict__ b2,
                       float* __restrict__ out, int N) {
    int lane = threadIdx.x & 63;
    int g = lane >> 2;   // node sub-index within wave (0..15)
    int c = lane & 3;    // uint4 column: features [8c, 8c+8)
    int wavebase = ((blockIdx.x * blockDim.x + threadIdx.x) >> 6) * 16;
    int node = wavebase + g;
    bool alive = node < N;
    int nodeC = alive ? node : N - 1;
    const uint4* H = (const uint4*)hs2;
    float dn = dinv[nodeC];
    int beg = row_ptr[nodeC];
    int tot = alive ? deg[nodeC] : 0;
    uint4 selfv = H[(size_t)nodeC * 4 + c];   // issued early, consumed last
    int gbase = lane & 0x3C;                  // first lane of this group
    int wtot = tot;
    wtot = max(wtot, __shfl_xor(wtot, 4, 64));
    wtot = max(wtot, __shfl_xor(wtot, 8, 64));
    wtot = max(wtot, __shfl_xor(wtot, 16, 64));
    wtot = max(wtot, __shfl_xor(wtot, 32, 64));
    int nch = (wtot + 3) >> 2;
    v2f a0 = {0.f, 0.f}, a1_ = {0.f, 0.f}, a2 = {0.f, 0.f}, a3 = {0.f, 0.f};
    uint4 vA[4], vB[4];
    auto ISSUE = [&](uint4 (&vv)[4], int i) {
        int base = 4 * i;
        int jal = (base + c < tot) ? csr_src[beg + base + c] : 0;
#pragma unroll
        for (int e = 0; e < 4; ++e) {
            int j = __shfl(jal, gbase + e, 64);
            if (base + e < tot) vv[e] = H[(size_t)j * 4 + c];
        }
    };
    auto CONSUME = [&](uint4 (&vv)[4], int i) {
        int base = 4 * i;
#pragma unroll
        for (int e = 0; e < 4; ++e)
            if (base + e < tot) pkadd(a0, a1_, a2, a3, vv[e]);
    };
    if (nch > 0) {
        ISSUE(vA, 0);
        int i = 1;
        for (; i + 1 < nch; i += 2) {
            ISSUE(vB, i);     CONSUME(vA, i - 1);
            ISSUE(vA, i + 1); CONSUME(vB, i);
        }
        if (i < nch) { ISSUE(vB, i); CONSUME(vA, i - 1); CONSUME(vB, i); }
        else          CONSUME(vA, i - 1);
    }
    pkadd(a0, a1_, a2, a3, selfv);            // self-loop
    if (alive) {
        const float4* B = (const float4*)b2;
        float4 bv0 = B[2 * c], bv1 = B[2 * c + 1];
        float4 o0, o1;
        o0.x = fmaf(a0.x, dn, bv0.x);
        o0.y = fmaf(a0.y, dn, bv0.y);
        o0.z = fmaf(a1_.x, dn, bv0.z);
        o0.w = fmaf(a1_.y, dn, bv0.w);
        o1.x = fmaf(a2.x, dn, bv1.x);
        o1.y = fmaf(a2.y, dn, bv1.y);
        o1.z = fmaf(a3.x, dn, bv1.z);
        o1.w = fmaf(a3.y, dn, bv1.w);
        float4* O = (float4*)out;
        O[(size_t)node * 8 + 2 * c] = o0;
        O[(size_t)node * 8 + 2 * c + 1] = o1;
    }
}

extern "C" void kernel_launch(void* const* d_in, const int* in_sizes, int n_in,
                              void* d_out, int out_size, void* d_ws, size_t ws_size,
                              hipStream_t stream) {
    const float* x  = (const float*)d_in[0];
    const int*   idx = (const int*)d_in[1];
    const float* W1 = (const float*)d_in[2];
    const float* b1 = (const float*)d_in[3];
    const float* W2 = (const float*)d_in[4];
    const float* b2 = (const float*)d_in[5];
    float* out = (float*)d_out;

    const int N = in_sizes[0] / 128;   // 100000 (< 2^17, required by packing)
    const int E = in_sizes[1] / 2;     // 1600000
    const int nbuck = (N + NPB - 1) >> BSHIFT;        // 98 (<= NBMAX)
    const int PB = (E + BLK * EPT - 1) / (BLK * EPT); // 782

    // workspace layout (256B aligned)
    char* ws = (char*)d_ws;
    size_t off = 0;
    auto alloc = [&](size_t bytes) -> char* {
        char* p = ws + off;
        off = (off + bytes + 255) & ~(size_t)255;
        return p;
    };
    float* dinv     = (float*)alloc((size_t)N * 4);
    int*   row_ptr  = (int*)alloc((size_t)N * 4);
    int*   deg      = (int*)alloc((size_t)N * 4);
    int*   bcursor  = (int*)alloc((size_t)nbuck * 4);
    int*   csr_src  = (int*)alloc((size_t)nbuck * SLOTB * 4);   // 7.2 MB
    size_t ep_bytes = (size_t)nbuck * SLOTB * 4;                // 7.2 MB
    size_t h1_bytes = (size_t)N * 64 * 2;                       // 12.8 MB
    int*   edge_part = (int*)alloc(ep_bytes > h1_bytes ? ep_bytes : h1_bytes);
    ushort_t* a1b   = (ushort_t*)alloc((size_t)N * 64 * 2);
    ushort_t* hs1   = (ushort_t*)edge_part;   // alias: edge_part dead after k_csr
    ushort_t* hs2   = hs1;                    // alias: hs1 dead after k_agg1

    hipMemsetAsync(bcursor, 0, (size_t)nbuck * 4, stream);
    k_part<<<PB, BLK, 0, stream>>>(idx, bcursor, edge_part, E, nbuck);
    k_csr<<<nbuck, BLKC, 0, stream>>>(edge_part, bcursor, row_ptr, deg, dinv,
                                      csr_src, N, nbuck);
    k_gemm1<<<(N + 63) / 64, BLK, 0, stream>>>(x, W1, dinv, hs1, N);
    k_agg1<<<(N * 8 + BLK - 1) / BLK, BLK, 0, stream>>>(
        (const uint_t*)hs1, row_ptr, deg, csr_src, dinv, b1, a1b, N);
    k_gemm2<<<(N + 63) / 64, BLK, 0, stream>>>(a1b, W2, dinv, hs2, N);
    k_agg2<<<(N * 4 + BLK - 1) / BLK, BLK, 0, stream>>>(
        (const uint_t*)hs2, row_ptr, deg, csr_src, dinv, b2, out, N);
}

// Round 6
// 214.316 us; speedup vs baseline: 1.2164x; 1.0283x over previous
//
#include <hip/hip_runtime.h>

// GCN 2-layer: x[N,128] -> GCNConv(W1[128,64], b1) -> ReLU -> GCNConv(W2[64,32], b2)
// norm = dinv[src]*dinv[dst] factorized. Bucketed multisplit build (R4), bf16
// intermediates (R5), MFMA gemms (R8), dense per-bucket edge segments (R10),
// pre-scaled hs (R11), group-per-node aggs (R12), batched gather issue (R13),
// depth-2 agg pipeline + rank capture (R14, neutral -> aggs at issue floor).
// R15: remove instructions, not reorder them. (a) all fp32->bf16 via
// v_cvt_pk_bf16_f32 (1 op / 2 floats, RNE == old 3-op bit-hack). (b) W1^T/W2^T
// pre-converted to bf16 ONCE by an extra block appended to k_part; gemm
// W-staging becomes a uint4 copy. (c) k_csr scan: 20-barrier Hillis-Steele ->
// shfl wave-scan + LDS tree (2 barriers).
// R16: FIX R15's W2^T store bug: second uint4 of each 16-k block must read
// &b2[4*i] not &b2[2*i] (k 8..15 were k 4..11 duplicates -> absmax 0.41).

#define BLK 256
#define BLKC 1024        // k_csr block size
#define EPT 8            // edges/thread in k_part
#define CITER 18         // k_csr max edges/thread = ceil(SLOTB/BLKC)
#define BSHIFT 10        // nodes per bucket
#define NPB 1024         // 1 << BSHIFT
#define SLOTB 18432      // edge slots per bucket; lambda~16.3K, 16 sigma
#define NBMAX 128        // >= nbuck = ceil(N/NPB) = 98

typedef unsigned int uint_t;
typedef unsigned short ushort_t;
typedef __attribute__((ext_vector_type(2))) float v2f;      // v_pk_* pair
typedef __attribute__((ext_vector_type(8))) short bf16x8;   // MFMA A/B frag
typedef __attribute__((ext_vector_type(4))) float f32x4;    // MFMA C/D frag

// paired RNE f32->bf16: lo -> bits[15:0], hi -> bits[31:16] (1 VALU op)
__device__ __forceinline__ uint_t pkbf(float lo, float hi) {
    uint_t r;
    asm("v_cvt_pk_bf16_f32 %0, %1, %2" : "=v"(r) : "v"(lo), "v"(hi));
    return r;
}

// 8 bf16 (uint4) += into 4 float2 accumulators (v_pk_add_f32 path)
__device__ __forceinline__ void pkadd(v2f& a0, v2f& a1, v2f& a2, v2f& a3, uint4 v) {
    v2f p;
    p.x = __uint_as_float(v.x << 16); p.y = __uint_as_float(v.x & 0xffff0000u); a0 += p;
    p.x = __uint_as_float(v.y << 16); p.y = __uint_as_float(v.y & 0xffff0000u); a1 += p;
    p.x = __uint_as_float(v.z << 16); p.y = __uint_as_float(v.z & 0xffff0000u); a2 += p;
    p.x = __uint_as_float(v.w << 16); p.y = __uint_as_float(v.w & 0xffff0000u); a3 += p;
}

// int64-layout detection (wave-uniform, L2-hot)
__device__ __forceinline__ bool detect64(const int* __restrict__ idx) {
    int z = 0;
#pragma unroll
    for (int i = 1; i < 32; i += 2) z |= idx[i];
    return z == 0;
}

// ---- build pass 1: partition edges into DENSE per-bucket segments.
// Rank captured from the counting atomicAdd; placement pass has no atomics.
// Block PB (extra) converts W1->W1^T bf16 [64][128] and W2->W2^T bf16 [32][64]
// into wt (consumed by the gemms two dispatches later; stream-ordered safe).
__global__ void k_part(const int* __restrict__ idx, int* __restrict__ bcursor,
                       int* __restrict__ edge_part,
                       const float* __restrict__ W1, const float* __restrict__ W2,
                       ushort_t* __restrict__ wt, int E, int nbuck, int PB) {
    if (blockIdx.x == PB) {          // W-conversion block
        int t = threadIdx.x;
        int n = t >> 2, q = t & 3;   // W1^T row n (0..63), k-block q (32 k)
        uint_t buf[16];
#pragma unroll
        for (int i = 0; i < 16; ++i) {
            float a = W1[(size_t)(32 * q + 2 * i) * 64 + n];
            float b = W1[(size_t)(32 * q + 2 * i + 1) * 64 + n];
            buf[i] = pkbf(a, b);
        }
#pragma unroll
        for (int i = 0; i < 4; ++i)
            ((uint4*)wt)[(size_t)n * 16 + q * 4 + i] = *(uint4*)&buf[4 * i];
        if (t < 128) {               // W2^T row n2 (0..31), k-block q2 (16 k)
            int n2 = t >> 2, q2 = t & 3;
            uint_t b2[8];
#pragma unroll
            for (int i = 0; i < 8; ++i) {
                float a = W2[(size_t)(16 * q2 + 2 * i) * 32 + n2];
                float b = W2[(size_t)(16 * q2 + 2 * i + 1) * 32 + n2];
                b2[i] = pkbf(a, b);
            }
#pragma unroll
            for (int i = 0; i < 2; ++i)
                ((uint4*)(wt + 8192))[(size_t)n2 * 8 + q2 * 2 + i] = *(uint4*)&b2[4 * i];
        }
        return;
    }
    __shared__ int h[NBMAX];
    __shared__ int rb[NBMAX];
    bool is64 = detect64(idx);
    int t = threadIdx.x, blk = blockIdx.x;
    for (int i = t; i < nbuck; i += BLK) h[i] = 0;
    __syncthreads();
    int base = blk * (BLK * EPT) + t;
    int dst[EPT], src[EPT], rk[EPT];
#pragma unroll
    for (int k = 0; k < EPT; ++k) {
        int e = base + k * BLK;
        if (e < E) {
            if (is64) {
                uint2 dv = ((const uint2*)idx)[(size_t)E + e];   // int64 dst[e]
                uint2 sv = ((const uint2*)idx)[e];               // int64 src[e]
                dst[k] = (int)dv.x;
                src[k] = (int)sv.x;
            } else {
                dst[k] = idx[E + e];
                src[k] = idx[e];
            }
            rk[k] = atomicAdd(&h[dst[k] >> BSHIFT], 1);
        } else {
            dst[k] = -1;
        }
    }
    __syncthreads();
    for (int i = t; i < nbuck; i += BLK) {
        int c = h[i];
        rb[i] = c ? atomicAdd(&bcursor[i], c) : 0;
    }
    __syncthreads();
#pragma unroll
    for (int k = 0; k < EPT; ++k) {
        if (dst[k] >= 0) {
            int b = dst[k] >> BSHIFT;
            edge_part[(size_t)b * SLOTB + rb[b] + rk[k]] =
                src[k] | ((dst[k] & (NPB - 1)) << 17);
        }
    }
}

// ---- build pass 2: one 1024-thread block per bucket; emits row_ptr, deg,
// dinv, csr_src. Single edge sweep with rank capture; shfl wave-scan
// (2 barriers instead of 20).
__global__ __launch_bounds__(BLKC) void k_csr(
        const int* __restrict__ edge_part, const int* __restrict__ bcursor,
        int* __restrict__ row_ptr, int* __restrict__ deg, float* __restrict__ dinv,
        int* __restrict__ csr_src, int N, int nbuck) {
    __shared__ int cnt[NPB];
    __shared__ int off[NPB];
    __shared__ int wsum[16];
    int b = blockIdx.x, t = threadIdx.x;
    int node0 = b << BSHIFT;
    int nn = min(NPB, N - node0);
    int m = bcursor[b];                   // total edges in this bucket
    size_t ebase = (size_t)b * SLOTB;
    cnt[t] = 0;
    __syncthreads();
    int pp[CITER], rr[CITER];
#pragma unroll
    for (int it = 0; it < CITER; ++it) {
        int e = t + it * BLKC;
        if (e < m) {
            int p = edge_part[ebase + e];
            pp[it] = p;
            rr[it] = atomicAdd(&cnt[((unsigned)p) >> 17], 1);
        }
    }
    __syncthreads();
    // scan: shfl inclusive scan within each wave, then 16-entry wave-sum scan
    int cown = cnt[t];
    int xi = cown;
#pragma unroll
    for (int d = 1; d < 64; d <<= 1) {
        int y = __shfl_up(xi, d, 64);
        if ((t & 63) >= d) xi += y;
    }
    if ((t & 63) == 63) wsum[t >> 6] = xi;
    __syncthreads();
    if (t < 16) {
        int wv = wsum[t];
#pragma unroll
        for (int d = 1; d < 16; d <<= 1) {
            int y = __shfl_up(wv, d, 64);
            if (t >= d) wv += y;
        }
        wsum[t] = wv;   // inclusive wave sums
    }
    __syncthreads();
    int excl = xi - cown + ((t >= 64) ? wsum[(t >> 6) - 1] : 0);
    off[t] = excl;
    if (t < nn) {
        row_ptr[node0 + t] = (int)(ebase + excl);
        deg[node0 + t] = cown;
        dinv[node0 + t] = rsqrtf((float)(cown + 1));  // +1 self-loop
    }
    __syncthreads();
#pragma unroll
    for (int it = 0; it < CITER; ++it) {
        int e = t + it * BLKC;
        if (e < m) {
            int p = pp[it];
            int dlo = ((unsigned)p) >> 17;
            csr_src[ebase + off[dlo] + rr[it]] = p & 0x1FFFF;
        }
    }
}

// ---- layer 1 GEMM (MFMA bf16): 64 rows x 64 cols per block, 4 waves.
// hs1[i,f] = bf16((x @ W1)[i,f] * dinv[i])  -- PRE-SCALED (agg1 adds directly).
// W-staging is a pure uint4 copy of pre-converted W1^T bf16.
__global__ __launch_bounds__(256) void k_gemm1(
        const float* __restrict__ x, const ushort_t* __restrict__ wt,
        const float* __restrict__ dinv, ushort_t* __restrict__ hs1, int N) {
    __shared__ ushort_t xb[64][136];   // x tile, bf16 (+pad -> frag reads <=2-way)
    __shared__ ushort_t wb[64][136];   // W1^T (wb[n][k]), bf16
    int t = threadIdx.x;
    int rbase = blockIdx.x * 64;
    for (int i = t; i < 1024; i += BLK) {       // 4 iters: uint4 copy
        int n = i >> 4, q = i & 15;
        uint4 v = ((const uint4*)wt)[i];
        *(uint4*)&wb[n][8 * q] = v;
    }
    for (int i = t; i < 2048; i += BLK) {
        int r = i >> 5, c4 = i & 31;
        int rr = rbase + r; if (rr >= N) rr = N - 1;
        float4 v = ((const float4*)x)[(size_t)rr * 32 + c4];
        uint2 p;
        p.x = pkbf(v.x, v.y);
        p.y = pkbf(v.z, v.w);
        *(uint2*)&xb[r][4 * c4] = p;
    }
    __syncthreads();
    int w = t >> 6, l = t & 63;
    int lane16 = l & 15, quad = l >> 4;
    int mrow = 16 * w + lane16;
    f32x4 acc0 = {0.f, 0.f, 0.f, 0.f}, acc1 = {0.f, 0.f, 0.f, 0.f};
    f32x4 acc2 = {0.f, 0.f, 0.f, 0.f}, acc3 = {0.f, 0.f, 0.f, 0.f};
#pragma unroll
    for (int kk = 0; kk < 4; ++kk) {
        int k0 = kk * 32 + quad * 8;
        bf16x8 a  = *(const bf16x8*)&xb[mrow][k0];
        bf16x8 b0 = *(const bf16x8*)&wb[lane16][k0];
        bf16x8 b1 = *(const bf16x8*)&wb[lane16 + 16][k0];
        bf16x8 b2 = *(const bf16x8*)&wb[lane16 + 32][k0];
        bf16x8 b3 = *(const bf16x8*)&wb[lane16 + 48][k0];
        acc0 = __builtin_amdgcn_mfma_f32_16x16x32_bf16(a, b0, acc0, 0, 0, 0);
        acc1 = __builtin_amdgcn_mfma_f32_16x16x32_bf16(a, b1, acc1, 0, 0, 0);
        acc2 = __builtin_amdgcn_mfma_f32_16x16x32_bf16(a, b2, acc2, 0, 0, 0);
        acc3 = __builtin_amdgcn_mfma_f32_16x16x32_bf16(a, b3, acc3, 0, 0, 0);
    }
    __syncthreads();
    int orow = 16 * w + quad * 4;   // D: row = quad*4+reg, col = lane16 (+16c)
    float d0 = dinv[min(rbase + orow + 0, N - 1)];
    float d1 = dinv[min(rbase + orow + 1, N - 1)];
    float d2 = dinv[min(rbase + orow + 2, N - 1)];
    float d3 = dinv[min(rbase + orow + 3, N - 1)];
    uint_t u;
    u = pkbf(acc0.x * d0, acc0.y * d1);
    xb[orow + 0][lane16] = (ushort_t)u;  xb[orow + 1][lane16] = (ushort_t)(u >> 16);
    u = pkbf(acc0.z * d2, acc0.w * d3);
    xb[orow + 2][lane16] = (ushort_t)u;  xb[orow + 3][lane16] = (ushort_t)(u >> 16);
    u = pkbf(acc1.x * d0, acc1.y * d1);
    xb[orow + 0][lane16 + 16] = (ushort_t)u;  xb[orow + 1][lane16 + 16] = (ushort_t)(u >> 16);
    u = pkbf(acc1.z * d2, acc1.w * d3);
    xb[orow + 2][lane16 + 16] = (ushort_t)u;  xb[orow + 3][lane16 + 16] = (ushort_t)(u >> 16);
    u = pkbf(acc2.x * d0, acc2.y * d1);
    xb[orow + 0][lane16 + 32] = (ushort_t)u;  xb[orow + 1][lane16 + 32] = (ushort_t)(u >> 16);
    u = pkbf(acc2.z * d2, acc2.w * d3);
    xb[orow + 2][lane16 + 32] = (ushort_t)u;  xb[orow + 3][lane16 + 32] = (ushort_t)(u >> 16);
    u = pkbf(acc3.x * d0, acc3.y * d1);
    xb[orow + 0][lane16 + 48] = (ushort_t)u;  xb[orow + 1][lane16 + 48] = (ushort_t)(u >> 16);
    u = pkbf(acc3.z * d2, acc3.w * d3);
    xb[orow + 2][lane16 + 48] = (ushort_t)u;  xb[orow + 3][lane16 + 48] = (ushort_t)(u >> 16);
    __syncthreads();
    for (int i = t; i < 512; i += BLK) {
        int r = i >> 3, c8 = i & 7;
        int rr = rbase + r;
        if (rr < N) {
            uint4 v = *(const uint4*)&xb[r][8 * c8];
            *(uint4*)&hs1[(size_t)rr * 64 + 8 * c8] = v;
        }
    }
}

// ---- layer 1 aggregation: 8 lanes per node, 8 nodes per wave.
// Depth-2 pipeline: ISSUE(i+1) before CONSUME(i), two named buffers.
__global__ void k_agg1(const uint_t* __restrict__ hs1, const int* __restrict__ row_ptr,
                       const int* __restrict__ deg, const int* __restrict__ csr_src,
                       const float* __restrict__ dinv, const float* __restrict__ b1,
                       ushort_t* __restrict__ a1b, int N) {
    int lane = threadIdx.x & 63;
    int g = lane >> 3;   // node sub-index within wave (0..7)
    int c = lane & 7;    // uint4 column: features [8c, 8c+8)
    int wavebase = ((blockIdx.x * blockDim.x + threadIdx.x) >> 6) * 8;
    int node = wavebase + g;
    bool alive = node < N;
    int nodeC = alive ? node : N - 1;
    const uint4* H = (const uint4*)hs1;
    float dn = dinv[nodeC];
    int beg = row_ptr[nodeC];
    int tot = alive ? deg[nodeC] : 0;
    uint4 selfv = H[(size_t)nodeC * 8 + c];   // issued early, consumed last
    int gbase = lane & 0x38;                  // first lane of this group
    // wave-uniform chunk count (max degree over the 8 nodes)
    int wtot = tot;
    wtot = max(wtot, __shfl_xor(wtot, 8, 64));
    wtot = max(wtot, __shfl_xor(wtot, 16, 64));
    wtot = max(wtot, __shfl_xor(wtot, 32, 64));
    int nch = (wtot + 7) >> 3;
    v2f a0 = {0.f, 0.f}, a1_ = {0.f, 0.f}, a2 = {0.f, 0.f}, a3 = {0.f, 0.f};
    uint4 vA[8], vB[8];
    auto ISSUE = [&](uint4 (&vv)[8], int i) {
        int base = 8 * i;
        int jal = (base + c < tot) ? csr_src[beg + base + c] : 0;
#pragma unroll
        for (int e = 0; e < 8; ++e) {
            int j = __shfl(jal, gbase + e, 64);
            if (base + e < tot) vv[e] = H[(size_t)j * 8 + c];
        }
    };
    auto CONSUME = [&](uint4 (&vv)[8], int i) {
        int base = 8 * i;
#pragma unroll
        for (int e = 0; e < 8; ++e)
            if (base + e < tot) pkadd(a0, a1_, a2, a3, vv[e]);
    };
    if (nch > 0) {
        ISSUE(vA, 0);
        int i = 1;
        for (; i + 1 < nch; i += 2) {
            ISSUE(vB, i);     CONSUME(vA, i - 1);
            ISSUE(vA, i + 1); CONSUME(vB, i);
        }
        if (i < nch) { ISSUE(vB, i); CONSUME(vA, i - 1); CONSUME(vB, i); }
        else          CONSUME(vA, i - 1);
    }
    pkadd(a0, a1_, a2, a3, selfv);            // self-loop
    if (alive) {
        const float4* B = (const float4*)b1;
        float4 bv0 = B[2 * c], bv1 = B[2 * c + 1];
        float o0 = fmaxf(fmaf(a0.x, dn, bv0.x), 0.f);
        float o1 = fmaxf(fmaf(a0.y, dn, bv0.y), 0.f);
        float o2 = fmaxf(fmaf(a1_.x, dn, bv0.z), 0.f);
        float o3 = fmaxf(fmaf(a1_.y, dn, bv0.w), 0.f);
        float o4 = fmaxf(fmaf(a2.x, dn, bv1.x), 0.f);
        float o5 = fmaxf(fmaf(a2.y, dn, bv1.y), 0.f);
        float o6 = fmaxf(fmaf(a3.x, dn, bv1.z), 0.f);
        float o7 = fmaxf(fmaf(a3.y, dn, bv1.w), 0.f);
        uint4 o;
        o.x = pkbf(o0, o1);
        o.y = pkbf(o2, o3);
        o.z = pkbf(o4, o5);
        o.w = pkbf(o6, o7);
        ((uint4*)a1b)[(size_t)node * 8 + c] = o;   // wave writes 1KB contiguous
    }
}

// ---- layer 2 GEMM (MFMA bf16): 64 rows x 32 cols per block, 4 waves.
// hs2[i,f] = bf16((a1 @ W2)[i,f] * dinv[i])  -- pre-scaled (agg2 adds directly).
__global__ __launch_bounds__(256) void k_gemm2(
        const ushort_t* __restrict__ a1b, const ushort_t* __restrict__ wt,
        const float* __restrict__ dinv, ushort_t* __restrict__ hs2, int N) {
    __shared__ ushort_t ab[64][72];
    __shared__ ushort_t wb[32][72];
    int t = threadIdx.x;
    int rbase = blockIdx.x * 64;
    for (int i = t; i < 256; i += BLK) {        // 1 iter: uint4 copy of W2^T
        int n = i >> 3, q = i & 7;
        uint4 v = ((const uint4*)(wt + 8192))[i];
        *(uint4*)&wb[n][8 * q] = v;
    }
    for (int i = t; i < 512; i += BLK) {
        int r = i >> 3, c8 = i & 7;
        int rr = rbase + r; if (rr >= N) rr = N - 1;
        uint4 v = ((const uint4*)a1b)[(size_t)rr * 8 + c8];
        *(uint4*)&ab[r][8 * c8] = v;
    }
    __syncthreads();
    int w = t >> 6, l = t & 63;
    int lane16 = l & 15, quad = l >> 4;
    int mrow = 16 * w + lane16;
    f32x4 acc0 = {0.f, 0.f, 0.f, 0.f}, acc1 = {0.f, 0.f, 0.f, 0.f};
#pragma unroll
    for (int kk = 0; kk < 2; ++kk) {
        int k0 = kk * 32 + quad * 8;
        bf16x8 a  = *(const bf16x8*)&ab[mrow][k0];
        bf16x8 b0 = *(const bf16x8*)&wb[lane16][k0];
        bf16x8 b1 = *(const bf16x8*)&wb[lane16 + 16][k0];
        acc0 = __builtin_amdgcn_mfma_f32_16x16x32_bf16(a, b0, acc0, 0, 0, 0);
        acc1 = __builtin_amdgcn_mfma_f32_16x16x32_bf16(a, b1, acc1, 0, 0, 0);
    }
    __syncthreads();
    int orow = 16 * w + quad * 4;
    float d0 = dinv[min(rbase + orow + 0, N - 1)];
    float d1 = dinv[min(rbase + orow + 1, N - 1)];
    float d2 = dinv[min(rbase + orow + 2, N - 1)];
    float d3 = dinv[min(rbase + orow + 3, N - 1)];
    uint_t u;
    u = pkbf(acc0.x * d0, acc0.y * d1);
    ab[orow + 0][lane16] = (ushort_t)u;  ab[orow + 1][lane16] = (ushort_t)(u >> 16);
    u = pkbf(acc0.z * d2, acc0.w * d3);
    ab[orow + 2][lane16] = (ushort_t)u;  ab[orow + 3][lane16] = (ushort_t)(u >> 16);
    u = pkbf(acc1.x * d0, acc1.y * d1);
    ab[orow + 0][lane16 + 16] = (ushort_t)u;  ab[orow + 1][lane16 + 16] = (ushort_t)(u >> 16);
    u = pkbf(acc1.z * d2, acc1.w * d3);
    ab[orow + 2][lane16 + 16] = (ushort_t)u;  ab[orow + 3][lane16 + 16] = (ushort_t)(u >> 16);
    __syncthreads();
    for (int i = t; i < 256; i += BLK) {
        int r = i >> 2, c4 = i & 3;
        int rr = rbase + r;
        if (rr < N) {
            uint4 v = *(const uint4*)&ab[r][8 * c4];
            *(uint4*)&hs2[(size_t)rr * 32 + 8 * c4] = v;
        }
    }
}

// ---- layer 2 aggregation: 4 lanes per node, 16 nodes per wave; depth-2
// pipeline like agg1.
__global__ void k_agg2(const uint_t* __restrict__ hs2, const int* __restrict__ row_ptr,
                       const int* __restrict__ deg, const int* __restrict__ csr_src,
                       const float* __restrict__ dinv, const float* __restrict__ b2,
                       float* __restrict__ out, int N) {
    int lane = threadIdx.x & 63;
    int g = lane >> 2;   // node sub-index within wave (0..15)
    int c = lane & 3;    // uint4 column: features [8c, 8c+8)
    int wavebase = ((blockIdx.x * blockDim.x + threadIdx.x) >> 6) * 16;
    int node = wavebase + g;
    bool alive = node < N;
    int nodeC = alive ? node : N - 1;
    const uint4* H = (const uint4*)hs2;
    float dn = dinv[nodeC];
    int beg = row_ptr[nodeC];
    int tot = alive ? deg[nodeC] : 0;
    uint4 selfv = H[(size_t)nodeC * 4 + c];   // issued early, consumed last
    int gbase = lane & 0x3C;                  // first lane of this group
    int wtot = tot;
    wtot = max(wtot, __shfl_xor(wtot, 4, 64));
    wtot = max(wtot, __shfl_xor(wtot, 8, 64));
    wtot = max(wtot, __shfl_xor(wtot, 16, 64));
    wtot = max(wtot, __shfl_xor(wtot, 32, 64));
    int nch = (wtot + 3) >> 2;
    v2f a0 = {0.f, 0.f}, a1_ = {0.f, 0.f}, a2 = {0.f, 0.f}, a3 = {0.f, 0.f};
    uint4 vA[4], vB[4];
    auto ISSUE = [&](uint4 (&vv)[4], int i) {
        int base = 4 * i;
        int jal = (base + c < tot) ? csr_src[beg + base + c] : 0;
#pragma unroll
        for (int e = 0; e < 4; ++e) {
            int j = __shfl(jal, gbase + e, 64);
            if (base + e < tot) vv[e] = H[(size_t)j * 4 + c];
        }
    };
    auto CONSUME = [&](uint4 (&vv)[4], int i) {
        int base = 4 * i;
#pragma unroll
        for (int e = 0; e < 4; ++e)
            if (base + e < tot) pkadd(a0, a1_, a2, a3, vv[e]);
    };
    if (nch > 0) {
        ISSUE(vA, 0);
        int i = 1;
        for (; i + 1 < nch; i += 2) {
            ISSUE(vB, i);     CONSUME(vA, i - 1);
            ISSUE(vA, i + 1); CONSUME(vB, i);
        }
        if (i < nch) { ISSUE(vB, i); CONSUME(vA, i - 1); CONSUME(vB, i); }
        else          CONSUME(vA, i - 1);
    }
    pkadd(a0, a1_, a2, a3, selfv);            // self-loop
    if (alive) {
        const float4* B = (const float4*)b2;
        float4 bv0 = B[2 * c], bv1 = B[2 * c + 1];
        float4 o0, o1;
        o0.x = fmaf(a0.x, dn, bv0.x);
        o0.y = fmaf(a0.y, dn, bv0.y);
        o0.z = fmaf(a1_.x, dn, bv0.z);
        o0.w = fmaf(a1_.y, dn, bv0.w);
        o1.x = fmaf(a2.x, dn, bv1.x);
        o1.y = fmaf(a2.y, dn, bv1.y);
        o1.z = fmaf(a3.x, dn, bv1.z);
        o1.w = fmaf(a3.y, dn, bv1.w);
        float4* O = (float4*)out;
        O[(size_t)node * 8 + 2 * c] = o0;
        O[(size_t)node * 8 + 2 * c + 1] = o1;
    }
}

extern "C" void kernel_launch(void* const* d_in, const int* in_sizes, int n_in,
                              void* d_out, int out_size, void* d_ws, size_t ws_size,
                              hipStream_t stream) {
    const float* x  = (const float*)d_in[0];
    const int*   idx = (const int*)d_in[1];
    const float* W1 = (const float*)d_in[2];
    const float* b1 = (const float*)d_in[3];
    const float* W2 = (const float*)d_in[4];
    const float* b2 = (const float*)d_in[5];
    float* out = (float*)d_out;

    const int N = in_sizes[0] / 128;   // 100000 (< 2^17, required by packing)
    const int E = in_sizes[1] / 2;     // 1600000
    const int nbuck = (N + NPB - 1) >> BSHIFT;        // 98 (<= NBMAX)
    const int PB = (E + BLK * EPT - 1) / (BLK * EPT); // 782

    // workspace layout (256B aligned)
    char* ws = (char*)d_ws;
    size_t off = 0;
    auto alloc = [&](size_t bytes) -> char* {
        char* p = ws + off;
        off = (off + bytes + 255) & ~(size_t)255;
        return p;
    };
    float* dinv     = (float*)alloc((size_t)N * 4);
    int*   row_ptr  = (int*)alloc((size_t)N * 4);
    int*   deg      = (int*)alloc((size_t)N * 4);
    int*   bcursor  = (int*)alloc((size_t)nbuck * 4);
    ushort_t* wt    = (ushort_t*)alloc((size_t)(8192 + 2048) * 2);  // W1^T,W2^T bf16
    int*   csr_src  = (int*)alloc((size_t)nbuck * SLOTB * 4);   // 7.2 MB
    size_t ep_bytes = (size_t)nbuck * SLOTB * 4;                // 7.2 MB
    size_t h1_bytes = (size_t)N * 64 * 2;                       // 12.8 MB
    int*   edge_part = (int*)alloc(ep_bytes > h1_bytes ? ep_bytes : h1_bytes);
    ushort_t* a1b   = (ushort_t*)alloc((size_t)N * 64 * 2);
    ushort_t* hs1   = (ushort_t*)edge_part;   // alias: edge_part dead after k_csr
    ushort_t* hs2   = hs1;                    // alias: hs1 dead after k_agg1

    hipMemsetAsync(bcursor, 0, (size_t)nbuck * 4, stream);
    k_part<<<PB + 1, BLK, 0, stream>>>(idx, bcursor, edge_part, W1, W2, wt,
                                       E, nbuck, PB);
    k_csr<<<nbuck, BLKC, 0, stream>>>(edge_part, bcursor, row_ptr, deg, dinv,
                                      csr_src, N, nbuck);
    k_gemm1<<<(N + 63) / 64, BLK, 0, stream>>>(x, wt, dinv, hs1, N);
    k_agg1<<<(N * 8 + BLK - 1) / BLK, BLK, 0, stream>>>(
        (const uint_t*)hs1, row_ptr, deg, csr_src, dinv, b1, a1b, N);
    k_gemm2<<<(N + 63) / 64, BLK, 0, stream>>>(a1b, wt, dinv, hs2, N);
    k_agg2<<<(N * 4 + BLK - 1) / BLK, BLK, 0, stream>>>(
        (const uint_t*)hs2, row_ptr, deg, csr_src, dinv, b2, out, N);
}

// Round 8
// 207.459 us; speedup vs baseline: 1.2566x; 1.0330x over previous
//
#include <hip/hip_runtime.h>

// GCN 2-layer: x[N,128] -> GCNConv(W1[128,64], b1) -> ReLU -> GCNConv(W2[64,32], b2)
// norm = dinv[src]*dinv[dst] factorized. Bucketed multisplit build (R4), bf16
// intermediates (R5), MFMA gemms (R8), dense per-bucket edge segments (R10),
// pre-scaled hs (R11), group-per-node aggs (R12), batched gather issue (R13),
// rank capture (R14), pk-cvt + pre-converted W + 2-barrier scan (R15/R16).
// R17: (a) BSHIFT 10->9: k_csr ran 98 blocks on 256 CUs (158 idle, duration =
// per-block serial work); 512-node buckets -> 196 blocks, per-block work
// halved. (b) sentinel row N in hs1/hs2 (zeroed by gemm block 0): OOR edge
// slots map to j=N -> agg gathers+pkadds fully unconditional (removes the
// per-edge cmp+exec-mask ~25% of agg instr stream). (c) aggs back to single
// gather buffer (R14 depth-2 measured neutral; vA+vB cost 32 VGPRs).
// R18: identical resubmit of R17 (round 7 bench was an infra failure --
// "container failed twice" -- kernel never measured).

#define BLK 256
#define BLKC 1024        // k_csr block size
#define EPT 8            // edges/thread in k_part
#define CITER 10         // k_csr max edges/thread = SLOTB/BLKC
#define BSHIFT 9         // nodes per bucket
#define NPB 512          // 1 << BSHIFT
#define SLOTB 10240      // edge slots per bucket; lambda~8.2K, ~23 sigma
#define NBMAX 256        // >= nbuck = ceil(N/NPB) = 196

typedef unsigned int uint_t;
typedef unsigned short ushort_t;
typedef __attribute__((ext_vector_type(2))) float v2f;      // v_pk_* pair
typedef __attribute__((ext_vector_type(8))) short bf16x8;   // MFMA A/B frag
typedef __attribute__((ext_vector_type(4))) float f32x4;    // MFMA C/D frag

// paired RNE f32->bf16: lo -> bits[15:0], hi -> bits[31:16] (1 VALU op)
__device__ __forceinline__ uint_t pkbf(float lo, float hi) {
    uint_t r;
    asm("v_cvt_pk_bf16_f32 %0, %1, %2" : "=v"(r) : "v"(lo), "v"(hi));
    return r;
}

// 8 bf16 (uint4) += into 4 float2 accumulators (v_pk_add_f32 path)
__device__ __forceinline__ void pkadd(v2f& a0, v2f& a1, v2f& a2, v2f& a3, uint4 v) {
    v2f p;
    p.x = __uint_as_float(v.x << 16); p.y = __uint_as_float(v.x & 0xffff0000u); a0 += p;
    p.x = __uint_as_float(v.y << 16); p.y = __uint_as_float(v.y & 0xffff0000u); a1 += p;
    p.x = __uint_as_float(v.z << 16); p.y = __uint_as_float(v.z & 0xffff0000u); a2 += p;
    p.x = __uint_as_float(v.w << 16); p.y = __uint_as_float(v.w & 0xffff0000u); a3 += p;
}

// int64-layout detection (wave-uniform, L2-hot)
__device__ __forceinline__ bool detect64(const int* __restrict__ idx) {
    int z = 0;
#pragma unroll
    for (int i = 1; i < 32; i += 2) z |= idx[i];
    return z == 0;
}

// ---- build pass 1: partition edges into DENSE per-bucket segments.
// Rank captured from the counting atomicAdd; placement pass has no atomics.
// Block PB (extra) converts W1->W1^T bf16 [64][128] and W2->W2^T bf16 [32][64].
__global__ void k_part(const int* __restrict__ idx, int* __restrict__ bcursor,
                       int* __restrict__ edge_part,
                       const float* __restrict__ W1, const float* __restrict__ W2,
                       ushort_t* __restrict__ wt, int E, int nbuck, int PB) {
    if (blockIdx.x == PB) {          // W-conversion block
        int t = threadIdx.x;
        int n = t >> 2, q = t & 3;   // W1^T row n (0..63), k-block q (32 k)
        uint_t buf[16];
#pragma unroll
        for (int i = 0; i < 16; ++i) {
            float a = W1[(size_t)(32 * q + 2 * i) * 64 + n];
            float b = W1[(size_t)(32 * q + 2 * i + 1) * 64 + n];
            buf[i] = pkbf(a, b);
        }
#pragma unroll
        for (int i = 0; i < 4; ++i)
            ((uint4*)wt)[(size_t)n * 16 + q * 4 + i] = *(uint4*)&buf[4 * i];
        if (t < 128) {               // W2^T row n2 (0..31), k-block q2 (16 k)
            int n2 = t >> 2, q2 = t & 3;
            uint_t b2[8];
#pragma unroll
            for (int i = 0; i < 8; ++i) {
                float a = W2[(size_t)(16 * q2 + 2 * i) * 32 + n2];
                float b = W2[(size_t)(16 * q2 + 2 * i + 1) * 32 + n2];
                b2[i] = pkbf(a, b);
            }
#pragma unroll
            for (int i = 0; i < 2; ++i)
                ((uint4*)(wt + 8192))[(size_t)n2 * 8 + q2 * 2 + i] = *(uint4*)&b2[4 * i];
        }
        return;
    }
    __shared__ int h[NBMAX];
    __shared__ int rb[NBMAX];
    bool is64 = detect64(idx);
    int t = threadIdx.x, blk = blockIdx.x;
    for (int i = t; i < nbuck; i += BLK) h[i] = 0;
    __syncthreads();
    int base = blk * (BLK * EPT) + t;
    int dst[EPT], src[EPT], rk[EPT];
#pragma unroll
    for (int k = 0; k < EPT; ++k) {
        int e = base + k * BLK;
        if (e < E) {
            if (is64) {
                uint2 dv = ((const uint2*)idx)[(size_t)E + e];   // int64 dst[e]
                uint2 sv = ((const uint2*)idx)[e];               // int64 src[e]
                dst[k] = (int)dv.x;
                src[k] = (int)sv.x;
            } else {
                dst[k] = idx[E + e];
                src[k] = idx[e];
            }
            rk[k] = atomicAdd(&h[dst[k] >> BSHIFT], 1);
        } else {
            dst[k] = -1;
        }
    }
    __syncthreads();
    for (int i = t; i < nbuck; i += BLK) {
        int c = h[i];
        rb[i] = c ? atomicAdd(&bcursor[i], c) : 0;
    }
    __syncthreads();
#pragma unroll
    for (int k = 0; k < EPT; ++k) {
        if (dst[k] >= 0) {
            int b = dst[k] >> BSHIFT;
            edge_part[(size_t)b * SLOTB + rb[b] + rk[k]] =
                src[k] | ((dst[k] & (NPB - 1)) << 17);
        }
    }
}

// ---- build pass 2: one 1024-thread block per 512-node bucket; emits
// row_ptr, deg, dinv, csr_src. Single edge sweep with rank capture;
// shfl wave-scan over 512 entries (2 barriers).
__global__ __launch_bounds__(BLKC) void k_csr(
        const int* __restrict__ edge_part, const int* __restrict__ bcursor,
        int* __restrict__ row_ptr, int* __restrict__ deg, float* __restrict__ dinv,
        int* __restrict__ csr_src, int N, int nbuck) {
    __shared__ int cnt[NPB];
    __shared__ int off[NPB];
    __shared__ int wsum[8];
    int b = blockIdx.x, t = threadIdx.x;
    int node0 = b << BSHIFT;
    int nn = min(NPB, N - node0);
    int m = bcursor[b];                   // total edges in this bucket
    size_t ebase = (size_t)b * SLOTB;
    if (t < NPB) cnt[t] = 0;
    __syncthreads();
    int pp[CITER], rr[CITER];
#pragma unroll
    for (int it = 0; it < CITER; ++it) {
        int e = t + it * BLKC;
        if (e < m) {
            int p = edge_part[ebase + e];
            pp[it] = p;
            rr[it] = atomicAdd(&cnt[((unsigned)p) >> 17], 1);
        }
    }
    __syncthreads();
    // scan over 512 entries: waves 0..7 shfl-scan, 8-entry wave-sum scan
    int cown = 0, xi = 0;
    if (t < NPB) {
        cown = cnt[t];
        xi = cown;
#pragma unroll
        for (int d = 1; d < 64; d <<= 1) {
            int y = __shfl_up(xi, d, 64);
            if ((t & 63) >= d) xi += y;
        }
        if ((t & 63) == 63) wsum[t >> 6] = xi;
    }
    __syncthreads();
    if (t < 8) {
        int wv = wsum[t];
#pragma unroll
        for (int d = 1; d < 8; d <<= 1) {
            int y = __shfl_up(wv, d, 64);
            if (t >= d) wv += y;
        }
        wsum[t] = wv;   // inclusive wave sums
    }
    __syncthreads();
    if (t < NPB) {
        int excl = xi - cown + ((t >= 64) ? wsum[(t >> 6) - 1] : 0);
        off[t] = excl;
        if (t < nn) {
            row_ptr[node0 + t] = (int)(ebase + excl);
            deg[node0 + t] = cown;
            dinv[node0 + t] = rsqrtf((float)(cown + 1));  // +1 self-loop
        }
    }
    __syncthreads();
#pragma unroll
    for (int it = 0; it < CITER; ++it) {
        int e = t + it * BLKC;
        if (e < m) {
            int p = pp[it];
            int dlo = ((unsigned)p) >> 17;
            csr_src[ebase + off[dlo] + rr[it]] = p & 0x1FFFF;
        }
    }
}

// ---- layer 1 GEMM (MFMA bf16): 64 rows x 64 cols per block, 4 waves.
// hs1[i,f] = bf16((x @ W1)[i,f] * dinv[i])  -- PRE-SCALED (agg1 adds directly).
// Block 0 also zeroes sentinel row N (gathered by OOR edge slots in agg1).
__global__ __launch_bounds__(256) void k_gemm1(
        const float* __restrict__ x, const ushort_t* __restrict__ wt,
        const float* __restrict__ dinv, ushort_t* __restrict__ hs1, int N) {
    __shared__ ushort_t xb[64][136];   // x tile, bf16 (+pad -> frag reads <=2-way)
    __shared__ ushort_t wb[64][136];   // W1^T (wb[n][k]), bf16
    int t = threadIdx.x;
    int rbase = blockIdx.x * 64;
    if (blockIdx.x == 0 && t < 8) {    // sentinel row N = zeros (128 B)
        uint4 z = {0u, 0u, 0u, 0u};
        ((uint4*)hs1)[(size_t)N * 8 + t] = z;
    }
    for (int i = t; i < 1024; i += BLK) {       // 4 iters: uint4 copy
        int n = i >> 4, q = i & 15;
        uint4 v = ((const uint4*)wt)[i];
        *(uint4*)&wb[n][8 * q] = v;
    }
    for (int i = t; i < 2048; i += BLK) {
        int r = i >> 5, c4 = i & 31;
        int rr = rbase + r; if (rr >= N) rr = N - 1;
        float4 v = ((const float4*)x)[(size_t)rr * 32 + c4];
        uint2 p;
        p.x = pkbf(v.x, v.y);
        p.y = pkbf(v.z, v.w);
        *(uint2*)&xb[r][4 * c4] = p;
    }
    __syncthreads();
    int w = t >> 6, l = t & 63;
    int lane16 = l & 15, quad = l >> 4;
    int mrow = 16 * w + lane16;
    f32x4 acc0 = {0.f, 0.f, 0.f, 0.f}, acc1 = {0.f, 0.f, 0.f, 0.f};
    f32x4 acc2 = {0.f, 0.f, 0.f, 0.f}, acc3 = {0.f, 0.f, 0.f, 0.f};
#pragma unroll
    for (int kk = 0; kk < 4; ++kk) {
        int k0 = kk * 32 + quad * 8;
        bf16x8 a  = *(const bf16x8*)&xb[mrow][k0];
        bf16x8 b0 = *(const bf16x8*)&wb[lane16][k0];
        bf16x8 b1 = *(const bf16x8*)&wb[lane16 + 16][k0];
        bf16x8 b2 = *(const bf16x8*)&wb[lane16 + 32][k0];
        bf16x8 b3 = *(const bf16x8*)&wb[lane16 + 48][k0];
        acc0 = __builtin_amdgcn_mfma_f32_16x16x32_bf16(a, b0, acc0, 0, 0, 0);
        acc1 = __builtin_amdgcn_mfma_f32_16x16x32_bf16(a, b1, acc1, 0, 0, 0);
        acc2 = __builtin_amdgcn_mfma_f32_16x16x32_bf16(a, b2, acc2, 0, 0, 0);
        acc3 = __builtin_amdgcn_mfma_f32_16x16x32_bf16(a, b3, acc3, 0, 0, 0);
    }
    __syncthreads();
    int orow = 16 * w + quad * 4;   // D: row = quad*4+reg, col = lane16 (+16c)
    float d0 = dinv[min(rbase + orow + 0, N - 1)];
    float d1 = dinv[min(rbase + orow + 1, N - 1)];
    float d2 = dinv[min(rbase + orow + 2, N - 1)];
    float d3 = dinv[min(rbase + orow + 3, N - 1)];
    uint_t u;
    u = pkbf(acc0.x * d0, acc0.y * d1);
    xb[orow + 0][lane16] = (ushort_t)u;  xb[orow + 1][lane16] = (ushort_t)(u >> 16);
    u = pkbf(acc0.z * d2, acc0.w * d3);
    xb[orow + 2][lane16] = (ushort_t)u;  xb[orow + 3][lane16] = (ushort_t)(u >> 16);
    u = pkbf(acc1.x * d0, acc1.y * d1);
    xb[orow + 0][lane16 + 16] = (ushort_t)u;  xb[orow + 1][lane16 + 16] = (ushort_t)(u >> 16);
    u = pkbf(acc1.z * d2, acc1.w * d3);
    xb[orow + 2][lane16 + 16] = (ushort_t)u;  xb[orow + 3][lane16 + 16] = (ushort_t)(u >> 16);
    u = pkbf(acc2.x * d0, acc2.y * d1);
    xb[orow + 0][lane16 + 32] = (ushort_t)u;  xb[orow + 1][lane16 + 32] = (ushort_t)(u >> 16);
    u = pkbf(acc2.z * d2, acc2.w * d3);
    xb[orow + 2][lane16 + 32] = (ushort_t)u;  xb[orow + 3][lane16 + 32] = (ushort_t)(u >> 16);
    u = pkbf(acc3.x * d0, acc3.y * d1);
    xb[orow + 0][lane16 + 48] = (ushort_t)u;  xb[orow + 1][lane16 + 48] = (ushort_t)(u >> 16);
    u = pkbf(acc3.z * d2, acc3.w * d3);
    xb[orow + 2][lane16 + 48] = (ushort_t)u;  xb[orow + 3][lane16 + 48] = (ushort_t)(u >> 16);
    __syncthreads();
    for (int i = t; i < 512; i += BLK) {
        int r = i >> 3, c8 = i & 7;
        int rr = rbase + r;
        if (rr < N) {
            uint4 v = *(const uint4*)&xb[r][8 * c8];
            *(uint4*)&hs1[(size_t)rr * 64 + 8 * c8] = v;
        }
    }
}

// ---- layer 1 aggregation: 8 lanes per node, 8 nodes per wave. OOR edge
// slots gather sentinel row N (zeros) -> unconditional gathers + pkadds.
__global__ void k_agg1(const uint_t* __restrict__ hs1, const int* __restrict__ row_ptr,
                       const int* __restrict__ deg, const int* __restrict__ csr_src,
                       const float* __restrict__ dinv, const float* __restrict__ b1,
                       ushort_t* __restrict__ a1b, int N) {
    int lane = threadIdx.x & 63;
    int g = lane >> 3;   // node sub-index within wave (0..7)
    int c = lane & 7;    // uint4 column: features [8c, 8c+8)
    int wavebase = ((blockIdx.x * blockDim.x + threadIdx.x) >> 6) * 8;
    int node = wavebase + g;
    bool alive = node < N;
    int nodeC = alive ? node : N - 1;
    const uint4* H = (const uint4*)hs1;
    float dn = dinv[nodeC];
    int beg = row_ptr[nodeC];
    int tot = alive ? deg[nodeC] : 0;
    uint4 selfv = H[(size_t)nodeC * 8 + c];   // issued early, consumed last
    int gbase = lane & 0x38;                  // first lane of this group
    // wave-uniform chunk count (max degree over the 8 nodes)
    int wtot = tot;
    wtot = max(wtot, __shfl_xor(wtot, 8, 64));
    wtot = max(wtot, __shfl_xor(wtot, 16, 64));
    wtot = max(wtot, __shfl_xor(wtot, 32, 64));
    int nch = (wtot + 7) >> 3;
    v2f a0 = {0.f, 0.f}, a1_ = {0.f, 0.f}, a2 = {0.f, 0.f}, a3 = {0.f, 0.f};
    for (int i = 0; i < nch; ++i) {
        int base = 8 * i;
        int jal = (base + c < tot) ? csr_src[beg + base + c] : N;  // sentinel
        uint4 vv[8];
#pragma unroll
        for (int e = 0; e < 8; ++e) {         // unconditional gathers
            int j = __shfl(jal, gbase + e, 64);
            vv[e] = H[(size_t)j * 8 + c];
        }
#pragma unroll
        for (int e = 0; e < 8; ++e)           // unconditional accumulate
            pkadd(a0, a1_, a2, a3, vv[e]);
    }
    pkadd(a0, a1_, a2, a3, selfv);            // self-loop
    if (alive) {
        const float4* B = (const float4*)b1;
        float4 bv0 = B[2 * c], bv1 = B[2 * c + 1];
        float o0 = fmaxf(fmaf(a0.x, dn, bv0.x), 0.f);
        float o1 = fmaxf(fmaf(a0.y, dn, bv0.y), 0.f);
        float o2 = fmaxf(fmaf(a1_.x, dn, bv0.z), 0.f);
        float o3 = fmaxf(fmaf(a1_.y, dn, bv0.w), 0.f);
        float o4 = fmaxf(fmaf(a2.x, dn, bv1.x), 0.f);
        float o5 = fmaxf(fmaf(a2.y, dn, bv1.y), 0.f);
        float o6 = fmaxf(fmaf(a3.x, dn, bv1.z), 0.f);
        float o7 = fmaxf(fmaf(a3.y, dn, bv1.w), 0.f);
        uint4 o;
        o.x = pkbf(o0, o1);
        o.y = pkbf(o2, o3);
        o.z = pkbf(o4, o5);
        o.w = pkbf(o6, o7);
        ((uint4*)a1b)[(size_t)node * 8 + c] = o;   // wave writes 1KB contiguous
    }
}

// ---- layer 2 GEMM (MFMA bf16): 64 rows x 32 cols per block, 4 waves.
// hs2[i,f] = bf16((a1 @ W2)[i,f] * dinv[i])  -- pre-scaled (agg2 adds directly).
// Block 0 zeroes sentinel row N of hs2.
__global__ __launch_bounds__(256) void k_gemm2(
        const ushort_t* __restrict__ a1b, const ushort_t* __restrict__ wt,
        const float* __restrict__ dinv, ushort_t* __restrict__ hs2, int N) {
    __shared__ ushort_t ab[64][72];
    __shared__ ushort_t wb[32][72];
    int t = threadIdx.x;
    int rbase = blockIdx.x * 64;
    if (blockIdx.x == 0 && t < 4) {    // sentinel row N = zeros (64 B)
        uint4 z = {0u, 0u, 0u, 0u};
        ((uint4*)hs2)[(size_t)N * 4 + t] = z;
    }
    for (int i = t; i < 256; i += BLK) {        // 1 iter: uint4 copy of W2^T
        int n = i >> 3, q = i & 7;
        uint4 v = ((const uint4*)(wt + 8192))[i];
        *(uint4*)&wb[n][8 * q] = v;
    }
    for (int i = t; i < 512; i += BLK) {
        int r = i >> 3, c8 = i & 7;
        int rr = rbase + r; if (rr >= N) rr = N - 1;
        uint4 v = ((const uint4*)a1b)[(size_t)rr * 8 + c8];
        *(uint4*)&ab[r][8 * c8] = v;
    }
    __syncthreads();
    int w = t >> 6, l = t & 63;
    int lane16 = l & 15, quad = l >> 4;
    int mrow = 16 * w + lane16;
    f32x4 acc0 = {0.f, 0.f, 0.f, 0.f}, acc1 = {0.f, 0.f, 0.f, 0.f};
#pragma unroll
    for (int kk = 0; kk < 2; ++kk) {
        int k0 = kk * 32 + quad * 8;
        bf16x8 a  = *(const bf16x8*)&ab[mrow][k0];
        bf16x8 b0 = *(const bf16x8*)&wb[lane16][k0];
        bf16x8 b1 = *(const bf16x8*)&wb[lane16 + 16][k0];
        acc0 = __builtin_amdgcn_mfma_f32_16x16x32_bf16(a, b0, acc0, 0, 0, 0);
        acc1 = __builtin_amdgcn_mfma_f32_16x16x32_bf16(a, b1, acc1, 0, 0, 0);
    }
    __syncthreads();
    int orow = 16 * w + quad * 4;
    float d0 = dinv[min(rbase + orow + 0, N - 1)];
    float d1 = dinv[min(rbase + orow + 1, N - 1)];
    float d2 = dinv[min(rbase + orow + 2, N - 1)];
    float d3 = dinv[min(rbase + orow + 3, N - 1)];
    uint_t u;
    u = pkbf(acc0.x * d0, acc0.y * d1);
    ab[orow + 0][lane16] = (ushort_t)u;  ab[orow + 1][lane16] = (ushort_t)(u >> 16);
    u = pkbf(acc0.z * d2, acc0.w * d3);
    ab[orow + 2][lane16] = (ushort_t)u;  ab[orow + 3][lane16] = (ushort_t)(u >> 16);
    u = pkbf(acc1.x * d0, acc1.y * d1);
    ab[orow + 0][lane16 + 16] = (ushort_t)u;  ab[orow + 1][lane16 + 16] = (ushort_t)(u >> 16);
    u = pkbf(acc1.z * d2, acc1.w * d3);
    ab[orow + 2][lane16 + 16] = (ushort_t)u;  ab[orow + 3][lane16 + 16] = (ushort_t)(u >> 16);
    __syncthreads();
    for (int i = t; i < 256; i += BLK) {
        int r = i >> 2, c4 = i & 3;
        int rr = rbase + r;
        if (rr < N) {
            uint4 v = *(const uint4*)&ab[r][8 * c4];
            *(uint4*)&hs2[(size_t)rr * 32 + 8 * c4] = v;
        }
    }
}

// ---- layer 2 aggregation: 4 lanes per node, 16 nodes per wave; sentinel
// unconditional form like agg1.
__global__ void k_agg2(const uint_t* __restrict__ hs2, const int* __restrict__ row_ptr,
                       const int* __restrict__ deg, const int* __restrict__ csr_src,
                       const float* __restrict__ dinv, const float* __restrict__ b2,
                       float* __restrict__ out, int N) {
    int lane = threadIdx.x & 63;
    int g = lane >> 2;   // node sub-index within wave (0..15)
    int c = lane & 3;    // uint4 column: features [8c, 8c+8)
    int wavebase = ((blockIdx.x * blockDim.x + threadIdx.x) >> 6) * 16;
    int node = wavebase + g;
    bool alive = node < N;
    int nodeC = alive ? node : N - 1;
    const uint4* H = (const uint4*)hs2;
    float dn = dinv[nodeC];
    int beg = row_ptr[nodeC];
    int tot = alive ? deg[nodeC] : 0;
    uint4 selfv = H[(size_t)nodeC * 4 + c];   // issued early, consumed last
    int gbase = lane & 0x3C;                  // first lane of this group
    int wtot = tot;
    wtot = max(wtot, __shfl_xor(wtot, 4, 64));
    wtot = max(wtot, __shfl_xor(wtot, 8, 64));
    wtot = max(wtot, __shfl_xor(wtot, 16, 64));
    wtot = max(wtot, __shfl_xor(wtot, 32, 64));
    int nch = (wtot + 3) >> 2;
    v2f a0 = {0.f, 0.f}, a1_ = {0.f, 0.f}, a2 = {0.f, 0.f}, a3 = {0.f, 0.f};
    for (int i = 0; i < nch; ++i) {
        int base = 4 * i;
        int jal = (base + c < tot) ? csr_src[beg + base + c] : N;  // sentinel
        uint4 vv[4];
#pragma unroll
        for (int e = 0; e < 4; ++e) {         // unconditional gathers
            int j = __shfl(jal, gbase + e, 64);
            vv[e] = H[(size_t)j * 4 + c];
        }
#pragma unroll
        for (int e = 0; e < 4; ++e)           // unconditional accumulate
            pkadd(a0, a1_, a2, a3, vv[e]);
    }
    pkadd(a0, a1_, a2, a3, selfv);            // self-loop
    if (alive) {
        const float4* B = (const float4*)b2;
        float4 bv0 = B[2 * c], bv1 = B[2 * c + 1];
        float4 o0, o1;
        o0.x = fmaf(a0.x, dn, bv0.x);
        o0.y = fmaf(a0.y, dn, bv0.y);
        o0.z = fmaf(a1_.x, dn, bv0.z);
        o0.w = fmaf(a1_.y, dn, bv0.w);
        o1.x = fmaf(a2.x, dn, bv1.x);
        o1.y = fmaf(a2.y, dn, bv1.y);
        o1.z = fmaf(a3.x, dn, bv1.z);
        o1.w = fmaf(a3.y, dn, bv1.w);
        float4* O = (float4*)out;
        O[(size_t)node * 8 + 2 * c] = o0;
        O[(size_t)node * 8 + 2 * c + 1] = o1;
    }
}

extern "C" void kernel_launch(void* const* d_in, const int* in_sizes, int n_in,
                              void* d_out, int out_size, void* d_ws, size_t ws_size,
                              hipStream_t stream) {
    const float* x  = (const float*)d_in[0];
    const int*   idx = (const int*)d_in[1];
    const float* W1 = (const float*)d_in[2];
    const float* b1 = (const float*)d_in[3];
    const float* W2 = (const float*)d_in[4];
    const float* b2 = (const float*)d_in[5];
    float* out = (float*)d_out;

    const int N = in_sizes[0] / 128;   // 100000 (< 2^17, required by packing)
    const int E = in_sizes[1] / 2;     // 1600000
    const int nbuck = (N + NPB - 1) >> BSHIFT;        // 196 (<= NBMAX)
    const int PB = (E + BLK * EPT - 1) / (BLK * EPT); // 782

    // workspace layout (256B aligned)
    char* ws = (char*)d_ws;
    size_t off = 0;
    auto alloc = [&](size_t bytes) -> char* {
        char* p = ws + off;
        off = (off + bytes + 255) & ~(size_t)255;
        return p;
    };
    float* dinv     = (float*)alloc((size_t)N * 4);
    int*   row_ptr  = (int*)alloc((size_t)N * 4);
    int*   deg      = (int*)alloc((size_t)N * 4);
    int*   bcursor  = (int*)alloc((size_t)nbuck * 4);
    ushort_t* wt    = (ushort_t*)alloc((size_t)(8192 + 2048) * 2);  // W1^T,W2^T bf16
    int*   csr_src  = (int*)alloc((size_t)nbuck * SLOTB * 4);   // 8.0 MB
    size_t ep_bytes = (size_t)nbuck * SLOTB * 4;                // 8.0 MB
    size_t h1_bytes = (size_t)(N + 1) * 64 * 2;                 // 12.8 MB (+sentinel)
    int*   edge_part = (int*)alloc(ep_bytes > h1_bytes ? ep_bytes : h1_bytes);
    ushort_t* a1b   = (ushort_t*)alloc((size_t)N * 64 * 2);
    ushort_t* hs1   = (ushort_t*)edge_part;   // alias: edge_part dead after k_csr
    ushort_t* hs2   = hs1;                    // alias: hs1 dead after k_agg1

    hipMemsetAsync(bcursor, 0, (size_t)nbuck * 4, stream);
    k_part<<<PB + 1, BLK, 0, stream>>>(idx, bcursor, edge_part, W1, W2, wt,
                                       E, nbuck, PB);
    k_csr<<<nbuck, BLKC, 0, stream>>>(edge_part, bcursor, row_ptr, deg, dinv,
                                      csr_src, N, nbuck);
    k_gemm1<<<(N + 63) / 64, BLK, 0, stream>>>(x, wt, dinv, hs1, N);
    k_agg1<<<(N * 8 + BLK - 1) / BLK, BLK, 0, stream>>>(
        (const uint_t*)hs1, row_ptr, deg, csr_src, dinv, b1, a1b, N);
    k_gemm2<<<(N + 63) / 64, BLK, 0, stream>>>(a1b, wt, dinv, hs2, N);
    k_agg2<<<(N * 4 + BLK - 1) / BLK, BLK, 0, stream>>>(
        (const uint_t*)hs2, row_ptr, deg, csr_src, dinv, b2, out, N);
}

// Round 9
// 199.757 us; speedup vs baseline: 1.3051x; 1.0386x over previous
//
#include <hip/hip_runtime.h>

// GCN 2-layer: x[N,128] -> GCNConv(W1[128,64], b1) -> ReLU -> GCNConv(W2[64,32], b2)
// norm = dinv[src]*dinv[dst] factorized. Bucketed multisplit build (R4), bf16
// intermediates (R5), MFMA gemms (R8), dense per-bucket edge segments (R10),
// pre-scaled hs (R11), group-per-node aggs (R12), batched gather issue (R13),
// rank capture (R14), pk-cvt + pre-converted W + 2-barrier scan (R15/R16),
// 512-node buckets + sentinel-row unconditional aggs (R17/R18).
// R19: gemm2 FUSED into agg1's epilogue. An agg1 block holds exactly 32
// complete a1 rows at epilogue (4 waves x 8 nodes x 8 feat/lane): write
// relu'd bf16 rows to a 32x72 LDS tile, barrier, 4 waves run the verified
// k_gemm2 MFMA pattern (wave w -> 16-row stripe w&1, 16-col stripe w>>1,
// K=64 = 2 MFMA), scale by dinv[row], store hs2. Removes the gemm2 dispatch
// (~6us + launch) and the a1b 12.8MB write + 12.8MB read. hs2 moves to the
// old a1b slot -- it must NOT alias hs1 (other blocks still gather hs1).

#define BLK 256
#define BLKC 1024        // k_csr block size
#define EPT 8            // edges/thread in k_part
#define CITER 10         // k_csr max edges/thread = SLOTB/BLKC
#define BSHIFT 9         // nodes per bucket
#define NPB 512          // 1 << BSHIFT
#define SLOTB 10240      // edge slots per bucket; lambda~8.2K, ~23 sigma
#define NBMAX 256        // >= nbuck = ceil(N/NPB) = 196

typedef unsigned int uint_t;
typedef unsigned short ushort_t;
typedef __attribute__((ext_vector_type(2))) float v2f;      // v_pk_* pair
typedef __attribute__((ext_vector_type(8))) short bf16x8;   // MFMA A/B frag
typedef __attribute__((ext_vector_type(4))) float f32x4;    // MFMA C/D frag

// paired RNE f32->bf16: lo -> bits[15:0], hi -> bits[31:16] (1 VALU op)
__device__ __forceinline__ uint_t pkbf(float lo, float hi) {
    uint_t r;
    asm("v_cvt_pk_bf16_f32 %0, %1, %2" : "=v"(r) : "v"(lo), "v"(hi));
    return r;
}

// 8 bf16 (uint4) += into 4 float2 accumulators (v_pk_add_f32 path)
__device__ __forceinline__ void pkadd(v2f& a0, v2f& a1, v2f& a2, v2f& a3, uint4 v) {
    v2f p;
    p.x = __uint_as_float(v.x << 16); p.y = __uint_as_float(v.x & 0xffff0000u); a0 += p;
    p.x = __uint_as_float(v.y << 16); p.y = __uint_as_float(v.y & 0xffff0000u); a1 += p;
    p.x = __uint_as_float(v.z << 16); p.y = __uint_as_float(v.z & 0xffff0000u); a2 += p;
    p.x = __uint_as_float(v.w << 16); p.y = __uint_as_float(v.w & 0xffff0000u); a3 += p;
}

// int64-layout detection (wave-uniform, L2-hot)
__device__ __forceinline__ bool detect64(const int* __restrict__ idx) {
    int z = 0;
#pragma unroll
    for (int i = 1; i < 32; i += 2) z |= idx[i];
    return z == 0;
}

// ---- build pass 1: partition edges into DENSE per-bucket segments.
// Rank captured from the counting atomicAdd; placement pass has no atomics.
// Block PB (extra) converts W1->W1^T bf16 [64][128] and W2->W2^T bf16 [32][64].
__global__ void k_part(const int* __restrict__ idx, int* __restrict__ bcursor,
                       int* __restrict__ edge_part,
                       const float* __restrict__ W1, const float* __restrict__ W2,
                       ushort_t* __restrict__ wt, int E, int nbuck, int PB) {
    if (blockIdx.x == PB) {          // W-conversion block
        int t = threadIdx.x;
        int n = t >> 2, q = t & 3;   // W1^T row n (0..63), k-block q (32 k)
        uint_t buf[16];
#pragma unroll
        for (int i = 0; i < 16; ++i) {
            float a = W1[(size_t)(32 * q + 2 * i) * 64 + n];
            float b = W1[(size_t)(32 * q + 2 * i + 1) * 64 + n];
            buf[i] = pkbf(a, b);
        }
#pragma unroll
        for (int i = 0; i < 4; ++i)
            ((uint4*)wt)[(size_t)n * 16 + q * 4 + i] = *(uint4*)&buf[4 * i];
        if (t < 128) {               // W2^T row n2 (0..31), k-block q2 (16 k)
            int n2 = t >> 2, q2 = t & 3;
            uint_t b2[8];
#pragma unroll
            for (int i = 0; i < 8; ++i) {
                float a = W2[(size_t)(16 * q2 + 2 * i) * 32 + n2];
                float b = W2[(size_t)(16 * q2 + 2 * i + 1) * 32 + n2];
                b2[i] = pkbf(a, b);
            }
#pragma unroll
            for (int i = 0; i < 2; ++i)
                ((uint4*)(wt + 8192))[(size_t)n2 * 8 + q2 * 2 + i] = *(uint4*)&b2[4 * i];
        }
        return;
    }
    __shared__ int h[NBMAX];
    __shared__ int rb[NBMAX];
    bool is64 = detect64(idx);
    int t = threadIdx.x, blk = blockIdx.x;
    for (int i = t; i < nbuck; i += BLK) h[i] = 0;
    __syncthreads();
    int base = blk * (BLK * EPT) + t;
    int dst[EPT], src[EPT], rk[EPT];
#pragma unroll
    for (int k = 0; k < EPT; ++k) {
        int e = base + k * BLK;
        if (e < E) {
            if (is64) {
                uint2 dv = ((const uint2*)idx)[(size_t)E + e];   // int64 dst[e]
                uint2 sv = ((const uint2*)idx)[e];               // int64 src[e]
                dst[k] = (int)dv.x;
                src[k] = (int)sv.x;
            } else {
                dst[k] = idx[E + e];
                src[k] = idx[e];
            }
            rk[k] = atomicAdd(&h[dst[k] >> BSHIFT], 1);
        } else {
            dst[k] = -1;
        }
    }
    __syncthreads();
    for (int i = t; i < nbuck; i += BLK) {
        int c = h[i];
        rb[i] = c ? atomicAdd(&bcursor[i], c) : 0;
    }
    __syncthreads();
#pragma unroll
    for (int k = 0; k < EPT; ++k) {
        if (dst[k] >= 0) {
            int b = dst[k] >> BSHIFT;
            edge_part[(size_t)b * SLOTB + rb[b] + rk[k]] =
                src[k] | ((dst[k] & (NPB - 1)) << 17);
        }
    }
}

// ---- build pass 2: one 1024-thread block per 512-node bucket; emits
// row_ptr, deg, dinv, csr_src. Single edge sweep with rank capture;
// shfl wave-scan over 512 entries (2 barriers).
__global__ __launch_bounds__(BLKC) void k_csr(
        const int* __restrict__ edge_part, const int* __restrict__ bcursor,
        int* __restrict__ row_ptr, int* __restrict__ deg, float* __restrict__ dinv,
        int* __restrict__ csr_src, int N, int nbuck) {
    __shared__ int cnt[NPB];
    __shared__ int off[NPB];
    __shared__ int wsum[8];
    int b = blockIdx.x, t = threadIdx.x;
    int node0 = b << BSHIFT;
    int nn = min(NPB, N - node0);
    int m = bcursor[b];                   // total edges in this bucket
    size_t ebase = (size_t)b * SLOTB;
    if (t < NPB) cnt[t] = 0;
    __syncthreads();
    int pp[CITER], rr[CITER];
#pragma unroll
    for (int it = 0; it < CITER; ++it) {
        int e = t + it * BLKC;
        if (e < m) {
            int p = edge_part[ebase + e];
            pp[it] = p;
            rr[it] = atomicAdd(&cnt[((unsigned)p) >> 17], 1);
        }
    }
    __syncthreads();
    // scan over 512 entries: waves 0..7 shfl-scan, 8-entry wave-sum scan
    int cown = 0, xi = 0;
    if (t < NPB) {
        cown = cnt[t];
        xi = cown;
#pragma unroll
        for (int d = 1; d < 64; d <<= 1) {
            int y = __shfl_up(xi, d, 64);
            if ((t & 63) >= d) xi += y;
        }
        if ((t & 63) == 63) wsum[t >> 6] = xi;
    }
    __syncthreads();
    if (t < 8) {
        int wv = wsum[t];
#pragma unroll
        for (int d = 1; d < 8; d <<= 1) {
            int y = __shfl_up(wv, d, 64);
            if (t >= d) wv += y;
        }
        wsum[t] = wv;   // inclusive wave sums
    }
    __syncthreads();
    if (t < NPB) {
        int excl = xi - cown + ((t >= 64) ? wsum[(t >> 6) - 1] : 0);
        off[t] = excl;
        if (t < nn) {
            row_ptr[node0 + t] = (int)(ebase + excl);
            deg[node0 + t] = cown;
            dinv[node0 + t] = rsqrtf((float)(cown + 1));  // +1 self-loop
        }
    }
    __syncthreads();
#pragma unroll
    for (int it = 0; it < CITER; ++it) {
        int e = t + it * BLKC;
        if (e < m) {
            int p = pp[it];
            int dlo = ((unsigned)p) >> 17;
            csr_src[ebase + off[dlo] + rr[it]] = p & 0x1FFFF;
        }
    }
}

// ---- layer 1 GEMM (MFMA bf16): 64 rows x 64 cols per block, 4 waves.
// hs1[i,f] = bf16((x @ W1)[i,f] * dinv[i])  -- PRE-SCALED (agg1 adds directly).
// Block 0 also zeroes sentinel row N (gathered by OOR edge slots in agg1).
__global__ __launch_bounds__(256) void k_gemm1(
        const float* __restrict__ x, const ushort_t* __restrict__ wt,
        const float* __restrict__ dinv, ushort_t* __restrict__ hs1, int N) {
    __shared__ ushort_t xb[64][136];   // x tile, bf16 (+pad -> frag reads <=2-way)
    __shared__ ushort_t wb[64][136];   // W1^T (wb[n][k]), bf16
    int t = threadIdx.x;
    int rbase = blockIdx.x * 64;
    if (blockIdx.x == 0 && t < 8) {    // sentinel row N = zeros (128 B)
        uint4 z = {0u, 0u, 0u, 0u};
        ((uint4*)hs1)[(size_t)N * 8 + t] = z;
    }
    for (int i = t; i < 1024; i += BLK) {       // 4 iters: uint4 copy
        int n = i >> 4, q = i & 15;
        uint4 v = ((const uint4*)wt)[i];
        *(uint4*)&wb[n][8 * q] = v;
    }
    for (int i = t; i < 2048; i += BLK) {
        int r = i >> 5, c4 = i & 31;
        int rr = rbase + r; if (rr >= N) rr = N - 1;
        float4 v = ((const float4*)x)[(size_t)rr * 32 + c4];
        uint2 p;
        p.x = pkbf(v.x, v.y);
        p.y = pkbf(v.z, v.w);
        *(uint2*)&xb[r][4 * c4] = p;
    }
    __syncthreads();
    int w = t >> 6, l = t & 63;
    int lane16 = l & 15, quad = l >> 4;
    int mrow = 16 * w + lane16;
    f32x4 acc0 = {0.f, 0.f, 0.f, 0.f}, acc1 = {0.f, 0.f, 0.f, 0.f};
    f32x4 acc2 = {0.f, 0.f, 0.f, 0.f}, acc3 = {0.f, 0.f, 0.f, 0.f};
#pragma unroll
    for (int kk = 0; kk < 4; ++kk) {
        int k0 = kk * 32 + quad * 8;
        bf16x8 a  = *(const bf16x8*)&xb[mrow][k0];
        bf16x8 b0 = *(const bf16x8*)&wb[lane16][k0];
        bf16x8 b1 = *(const bf16x8*)&wb[lane16 + 16][k0];
        bf16x8 b2 = *(const bf16x8*)&wb[lane16 + 32][k0];
        bf16x8 b3 = *(const bf16x8*)&wb[lane16 + 48][k0];
        acc0 = __builtin_amdgcn_mfma_f32_16x16x32_bf16(a, b0, acc0, 0, 0, 0);
        acc1 = __builtin_amdgcn_mfma_f32_16x16x32_bf16(a, b1, acc1, 0, 0, 0);
        acc2 = __builtin_amdgcn_mfma_f32_16x16x32_bf16(a, b2, acc2, 0, 0, 0);
        acc3 = __builtin_amdgcn_mfma_f32_16x16x32_bf16(a, b3, acc3, 0, 0, 0);
    }
    __syncthreads();
    int orow = 16 * w + quad * 4;   // D: row = quad*4+reg, col = lane16 (+16c)
    float d0 = dinv[min(rbase + orow + 0, N - 1)];
    float d1 = dinv[min(rbase + orow + 1, N - 1)];
    float d2 = dinv[min(rbase + orow + 2, N - 1)];
    float d3 = dinv[min(rbase + orow + 3, N - 1)];
    uint_t u;
    u = pkbf(acc0.x * d0, acc0.y * d1);
    xb[orow + 0][lane16] = (ushort_t)u;  xb[orow + 1][lane16] = (ushort_t)(u >> 16);
    u = pkbf(acc0.z * d2, acc0.w * d3);
    xb[orow + 2][lane16] = (ushort_t)u;  xb[orow + 3][lane16] = (ushort_t)(u >> 16);
    u = pkbf(acc1.x * d0, acc1.y * d1);
    xb[orow + 0][lane16 + 16] = (ushort_t)u;  xb[orow + 1][lane16 + 16] = (ushort_t)(u >> 16);
    u = pkbf(acc1.z * d2, acc1.w * d3);
    xb[orow + 2][lane16 + 16] = (ushort_t)u;  xb[orow + 3][lane16 + 16] = (ushort_t)(u >> 16);
    u = pkbf(acc2.x * d0, acc2.y * d1);
    xb[orow + 0][lane16 + 32] = (ushort_t)u;  xb[orow + 1][lane16 + 32] = (ushort_t)(u >> 16);
    u = pkbf(acc2.z * d2, acc2.w * d3);
    xb[orow + 2][lane16 + 32] = (ushort_t)u;  xb[orow + 3][lane16 + 32] = (ushort_t)(u >> 16);
    u = pkbf(acc3.x * d0, acc3.y * d1);
    xb[orow + 0][lane16 + 48] = (ushort_t)u;  xb[orow + 1][lane16 + 48] = (ushort_t)(u >> 16);
    u = pkbf(acc3.z * d2, acc3.w * d3);
    xb[orow + 2][lane16 + 48] = (ushort_t)u;  xb[orow + 3][lane16 + 48] = (ushort_t)(u >> 16);
    __syncthreads();
    for (int i = t; i < 512; i += BLK) {
        int r = i >> 3, c8 = i & 7;
        int rr = rbase + r;
        if (rr < N) {
            uint4 v = *(const uint4*)&xb[r][8 * c8];
            *(uint4*)&hs1[(size_t)rr * 64 + 8 * c8] = v;
        }
    }
}

// ---- layer 1 aggregation + FUSED layer 2 GEMM. 8 lanes per node, 8 nodes
// per wave, 32 nodes per block. Sentinel-row unconditional gathers. Epilogue:
// relu'd a1 rows -> LDS tile -> 4-wave 32x64 @ 64x32 MFMA -> hs2 (pre-scaled
// by dinv[row]). hs2 does NOT alias hs1.
__global__ __launch_bounds__(256) void k_agg1(
        const uint_t* __restrict__ hs1, const int* __restrict__ row_ptr,
        const int* __restrict__ deg, const int* __restrict__ csr_src,
        const float* __restrict__ dinv, const float* __restrict__ b1,
        const ushort_t* __restrict__ wt, ushort_t* __restrict__ hs2, int N) {
    __shared__ ushort_t ab[32][72];    // a1 rows, bf16 (+pad)
    __shared__ ushort_t wb2[32][72];   // W2^T (wb2[n][k]), bf16
    int t = threadIdx.x;
    int lane = t & 63;
    int w = t >> 6;
    int g = lane >> 3;   // node sub-index within wave (0..7)
    int c = lane & 7;    // uint4 column: features [8c, 8c+8)
    int rbase = blockIdx.x * 32;
    int node = rbase + w * 8 + g;
    bool alive = node < N;
    int nodeC = alive ? node : N - 1;
    if (blockIdx.x == 0 && t < 4) {    // hs2 sentinel row N = zeros (64 B)
        uint4 z = {0u, 0u, 0u, 0u};
        ((uint4*)hs2)[(size_t)N * 4 + t] = z;
    }
    // stage W2^T: 256 uint4 = 1/thread
    {
        int n = t >> 3, q = t & 7;
        uint4 v = ((const uint4*)(wt + 8192))[t];
        *(uint4*)&wb2[n][8 * q] = v;
    }
    const uint4* H = (const uint4*)hs1;
    float dn = dinv[nodeC];
    int beg = row_ptr[nodeC];
    int tot = alive ? deg[nodeC] : 0;
    uint4 selfv = H[(size_t)nodeC * 8 + c];   // issued early, consumed last
    int gbase = lane & 0x38;                  // first lane of this group
    // wave-uniform chunk count (max degree over the 8 nodes)
    int wtot = tot;
    wtot = max(wtot, __shfl_xor(wtot, 8, 64));
    wtot = max(wtot, __shfl_xor(wtot, 16, 64));
    wtot = max(wtot, __shfl_xor(wtot, 32, 64));
    int nch = (wtot + 7) >> 3;
    v2f a0 = {0.f, 0.f}, a1_ = {0.f, 0.f}, a2 = {0.f, 0.f}, a3 = {0.f, 0.f};
    for (int i = 0; i < nch; ++i) {
        int base = 8 * i;
        int jal = (base + c < tot) ? csr_src[beg + base + c] : N;  // sentinel
        uint4 vv[8];
#pragma unroll
        for (int e = 0; e < 8; ++e) {         // unconditional gathers
            int j = __shfl(jal, gbase + e, 64);
            vv[e] = H[(size_t)j * 8 + c];
        }
#pragma unroll
        for (int e = 0; e < 8; ++e)           // unconditional accumulate
            pkadd(a0, a1_, a2, a3, vv[e]);
    }
    pkadd(a0, a1_, a2, a3, selfv);            // self-loop
    // a1 row (bias + relu) -> LDS tile (dead nodes write zeros)
    {
        const float4* B = (const float4*)b1;
        float4 bv0 = B[2 * c], bv1 = B[2 * c + 1];
        uint4 o = {0u, 0u, 0u, 0u};
        if (alive) {
            float o0 = fmaxf(fmaf(a0.x, dn, bv0.x), 0.f);
            float o1 = fmaxf(fmaf(a0.y, dn, bv0.y), 0.f);
            float o2 = fmaxf(fmaf(a1_.x, dn, bv0.z), 0.f);
            float o3 = fmaxf(fmaf(a1_.y, dn, bv0.w), 0.f);
            float o4 = fmaxf(fmaf(a2.x, dn, bv1.x), 0.f);
            float o5 = fmaxf(fmaf(a2.y, dn, bv1.y), 0.f);
            float o6 = fmaxf(fmaf(a3.x, dn, bv1.z), 0.f);
            float o7 = fmaxf(fmaf(a3.y, dn, bv1.w), 0.f);
            o.x = pkbf(o0, o1);
            o.y = pkbf(o2, o3);
            o.z = pkbf(o4, o5);
            o.w = pkbf(o6, o7);
        }
        *(uint4*)&ab[w * 8 + g][8 * c] = o;
    }
    __syncthreads();
    // fused mini-GEMM: 32x64 @ 64x32 (k_gemm2 pattern). wave w: row stripe
    // rt=w&1 (16 rows), col stripe ct=w>>1 (16 cols), K=64 -> 2 MFMA.
    int lane16 = lane & 15, quad = lane >> 4;
    int rt = w & 1, ct = w >> 1;
    int mrow = 16 * rt + lane16;
    f32x4 acc = {0.f, 0.f, 0.f, 0.f};
#pragma unroll
    for (int kk = 0; kk < 2; ++kk) {
        int k0 = kk * 32 + quad * 8;
        bf16x8 a = *(const bf16x8*)&ab[mrow][k0];
        bf16x8 b = *(const bf16x8*)&wb2[16 * ct + lane16][k0];
        acc = __builtin_amdgcn_mfma_f32_16x16x32_bf16(a, b, acc, 0, 0, 0);
    }
    __syncthreads();
    int orow = 16 * rt + quad * 4;   // D: row = quad*4+reg, col = 16ct+lane16
    int ocol = 16 * ct + lane16;
    float d0 = dinv[min(rbase + orow + 0, N - 1)];
    float d1 = dinv[min(rbase + orow + 1, N - 1)];
    float d2 = dinv[min(rbase + orow + 2, N - 1)];
    float d3 = dinv[min(rbase + orow + 3, N - 1)];
    uint_t u;
    u = pkbf(acc.x * d0, acc.y * d1);
    ab[orow + 0][ocol] = (ushort_t)u;  ab[orow + 1][ocol] = (ushort_t)(u >> 16);
    u = pkbf(acc.z * d2, acc.w * d3);
    ab[orow + 2][ocol] = (ushort_t)u;  ab[orow + 3][ocol] = (ushort_t)(u >> 16);
    __syncthreads();
    for (int i = t; i < 128; i += BLK) {
        int r = i >> 2, c4 = i & 3;
        int rr = rbase + r;
        if (rr < N) {
            uint4 v = *(const uint4*)&ab[r][8 * c4];
            ((uint4*)hs2)[(size_t)rr * 4 + c4] = v;
        }
    }
}

// ---- layer 2 aggregation: 4 lanes per node, 16 nodes per wave; sentinel
// unconditional form.
__global__ void k_agg2(const uint_t* __restrict__ hs2, const int* __restrict__ row_ptr,
                       const int* __restrict__ deg, const int* __restrict__ csr_src,
                       const float* __restrict__ dinv, const float* __restrict__ b2,
                       float* __restrict__ out, int N) {
    int lane = threadIdx.x & 63;
    int g = lane >> 2;   // node sub-index within wave (0..15)
    int c = lane & 3;    // uint4 column: features [8c, 8c+8)
    int wavebase = ((blockIdx.x * blockDim.x + threadIdx.x) >> 6) * 16;
    int node = wavebase + g;
    bool alive = node < N;
    int nodeC = alive ? node : N - 1;
    const uint4* H = (const uint4*)hs2;
    float dn = dinv[nodeC];
    int beg = row_ptr[nodeC];
    int tot = alive ? deg[nodeC] : 0;
    uint4 selfv = H[(size_t)nodeC * 4 + c];   // issued early, consumed last
    int gbase = lane & 0x3C;                  // first lane of this group
    int wtot = tot;
    wtot = max(wtot, __shfl_xor(wtot, 4, 64));
    wtot = max(wtot, __shfl_xor(wtot, 8, 64));
    wtot = max(wtot, __shfl_xor(wtot, 16, 64));
    wtot = max(wtot, __shfl_xor(wtot, 32, 64));
    int nch = (wtot + 3) >> 2;
    v2f a0 = {0.f, 0.f}, a1_ = {0.f, 0.f}, a2 = {0.f, 0.f}, a3 = {0.f, 0.f};
    for (int i = 0; i < nch; ++i) {
        int base = 4 * i;
        int jal = (base + c < tot) ? csr_src[beg + base + c] : N;  // sentinel
        uint4 vv[4];
#pragma unroll
        for (int e = 0; e < 4; ++e) {         // unconditional gathers
            int j = __shfl(jal, gbase + e, 64);
            vv[e] = H[(size_t)j * 4 + c];
        }
#pragma unroll
        for (int e = 0; e < 4; ++e)           // unconditional accumulate
            pkadd(a0, a1_, a2, a3, vv[e]);
    }
    pkadd(a0, a1_, a2, a3, selfv);            // self-loop
    if (alive) {
        const float4* B = (const float4*)b2;
        float4 bv0 = B[2 * c], bv1 = B[2 * c + 1];
        float4 o0, o1;
        o0.x = fmaf(a0.x, dn, bv0.x);
        o0.y = fmaf(a0.y, dn, bv0.y);
        o0.z = fmaf(a1_.x, dn, bv0.z);
        o0.w = fmaf(a1_.y, dn, bv0.w);
        o1.x = fmaf(a2.x, dn, bv1.x);
        o1.y = fmaf(a2.y, dn, bv1.y);
        o1.z = fmaf(a3.x, dn, bv1.z);
        o1.w = fmaf(a3.y, dn, bv1.w);
        float4* O = (float4*)out;
        O[(size_t)node * 8 + 2 * c] = o0;
        O[(size_t)node * 8 + 2 * c + 1] = o1;
    }
}

extern "C" void kernel_launch(void* const* d_in, const int* in_sizes, int n_in,
                              void* d_out, int out_size, void* d_ws, size_t ws_size,
                              hipStream_t stream) {
    const float* x  = (const float*)d_in[0];
    const int*   idx = (const int*)d_in[1];
    const float* W1 = (const float*)d_in[2];
    const float* b1 = (const float*)d_in[3];
    const float* W2 = (const float*)d_in[4];
    const float* b2 = (const float*)d_in[5];
    float* out = (float*)d_out;

    const int N = in_sizes[0] / 128;   // 100000 (< 2^17, required by packing)
    const int E = in_sizes[1] / 2;     // 1600000
    const int nbuck = (N + NPB - 1) >> BSHIFT;        // 196 (<= NBMAX)
    const int PB = (E + BLK * EPT - 1) / (BLK * EPT); // 782

    // workspace layout (256B aligned)
    char* ws = (char*)d_ws;
    size_t off = 0;
    auto alloc = [&](size_t bytes) -> char* {
        char* p = ws + off;
        off = (off + bytes + 255) & ~(size_t)255;
        return p;
    };
    float* dinv     = (float*)alloc((size_t)N * 4);
    int*   row_ptr  = (int*)alloc((size_t)N * 4);
    int*   deg      = (int*)alloc((size_t)N * 4);
    int*   bcursor  = (int*)alloc((size_t)nbuck * 4);
    ushort_t* wt    = (ushort_t*)alloc((size_t)(8192 + 2048) * 2);  // W1^T,W2^T bf16
    int*   csr_src  = (int*)alloc((size_t)nbuck * SLOTB * 4);   // 8.0 MB
    size_t ep_bytes = (size_t)nbuck * SLOTB * 4;                // 8.0 MB
    size_t h1_bytes = (size_t)(N + 1) * 64 * 2;                 // 12.8 MB (+sentinel)
    int*   edge_part = (int*)alloc(ep_bytes > h1_bytes ? ep_bytes : h1_bytes);
    ushort_t* hs2   = (ushort_t*)alloc((size_t)(N + 1) * 32 * 2);  // 6.4 MB (+sentinel)
    ushort_t* hs1   = (ushort_t*)edge_part;   // alias: edge_part dead after k_csr

    hipMemsetAsync(bcursor, 0, (size_t)nbuck * 4, stream);
    k_part<<<PB + 1, BLK, 0, stream>>>(idx, bcursor, edge_part, W1, W2, wt,
                                       E, nbuck, PB);
    k_csr<<<nbuck, BLKC, 0, stream>>>(edge_part, bcursor, row_ptr, deg, dinv,
                                      csr_src, N, nbuck);
    k_gemm1<<<(N + 63) / 64, BLK, 0, stream>>>(x, wt, dinv, hs1, N);
    k_agg1<<<(N * 8 + BLK - 1) / BLK, BLK, 0, stream>>>(
        (const uint_t*)hs1, row_ptr, deg, csr_src, dinv, b1, wt, hs2, N);
    k_agg2<<<(N * 4 + BLK - 1) / BLK, BLK, 0, stream>>>(
        (const uint_t*)hs2, row_ptr, deg, csr_src, dinv, b2, out, N);
}